// Round 4
// baseline (7706.013 us; speedup 1.0000x reference)
//
#include <hip/hip_runtime.h>
#include <hip/hip_bf16.h>

typedef __hip_bfloat16 bf16;

#define KHK 197376
#define OFF_WIN 0
#define OFF_BIN 49152
#define OFF_WMD 49280
#define OFF_BMD 65664
#define OFF_WOT 65792
#define OFF_BOT 98560
#define OFF_WSC 98816
#define OFF_BSC 197120

__device__ __forceinline__ float ldf(const float* p, size_t i){ return p[i]; }
__device__ __forceinline__ float ldf(const bf16* p, size_t i){ return __bfloat162float(p[i]); }
__device__ __forceinline__ void stf(float* p, size_t i, float v){ p[i] = v; }
__device__ __forceinline__ void stf(bf16* p, size_t i, float v){ p[i] = __float2bfloat16(v); }

// ---------------- input 1x1 conv: (16,3,64,64) -> (16,128,64,64) fp32 out ----------------
__global__ __launch_bounds__(256) void k_in_conv(const float* __restrict__ x,
    const float* __restrict__ w, const float* __restrict__ b, float* __restrict__ out){
  int idx = blockIdx.x*256 + threadIdx.x;          // 16*128*4096 total
  int s = idx & 4095;
  int o = (idx >> 12) & 127;
  int bi = idx >> 19;
  const float* xb = x + (size_t)bi*3*4096;
  out[idx] = b[o] + w[o*3+0]*xb[s] + w[o*3+1]*xb[4096+s] + w[o*3+2]*xb[8192+s];
}

// ---------------- sobel + concat: OUT fp32 (128ch) -> P bf16 (384ch) ----------------
__global__ __launch_bounds__(256) void k_sobel(const float* __restrict__ src,
    bf16* __restrict__ p, int H, int W){
  int S = H*W;
  int idx = blockIdx.x*256 + threadIdx.x;
  int s = idx % S;
  int c = (idx / S) & 127;
  int b = idx / (S*128);
  int y = s / W, x = s - y*W;
  const float* sb = src + ((size_t)b*128 + c)*S;
  float n[3][3];
  #pragma unroll
  for (int dy=0; dy<3; dy++)
    #pragma unroll
    for (int dx=0; dx<3; dx++){
      int yy = y + dy - 1, xx = x + dx - 1;
      n[dy][dx] = (yy>=0 && yy<H && xx>=0 && xx<W) ? sb[yy*W+xx] : 0.f;
    }
  float sx = (-n[0][0] + n[0][2] - 2.f*n[1][0] + 2.f*n[1][2] - n[2][0] + n[2][2]) * 0.125f;
  float sy = (-n[0][0] - 2.f*n[0][1] - n[0][2] + n[2][0] + 2.f*n[2][1] + n[2][2]) * 0.125f;
  bf16* pb = p + (size_t)b*384*S;
  stf(pb, (size_t)c*S + s,       n[1][1]);
  stf(pb, (size_t)(128+c)*S + s, sx);
  stf(pb, (size_t)(256+c)*S + s, sy);
}

// ---------------- instance norm in place (bf16), one block per (b,ch) ----------------
__global__ __launch_bounds__(256) void k_instnorm(bf16* __restrict__ p, int S){
  __shared__ float sA[256], sB[256];
  __shared__ float mInv[2];
  bf16* d = p + (size_t)blockIdx.x * S;
  float s = 0.f, s2 = 0.f;
  for (int i = threadIdx.x; i < S; i += 256){ float v = ldf(d,i); s += v; s2 += v*v; }
  sA[threadIdx.x] = s; sB[threadIdx.x] = s2;
  __syncthreads();
  for (int off = 128; off > 0; off >>= 1){
    if (threadIdx.x < off){ sA[threadIdx.x] += sA[threadIdx.x+off]; sB[threadIdx.x] += sB[threadIdx.x+off]; }
    __syncthreads();
  }
  if (threadIdx.x == 0){
    float m = sA[0] / (float)S;
    float var = sB[0] / (float)S - m*m;
    mInv[0] = m; mInv[1] = 1.f / sqrtf(var + 1e-5f);
  }
  __syncthreads();
  float m = mInv[0], inv = mInv[1];
  for (int i = threadIdx.x; i < S; i += 256) stf(d, i, (ldf(d,i) - m) * inv);
}

// ---- tiled GEMM: OUT[b][o][s] (+)= act(bias + sum_k W[o][k]*IN[b][k][s]), fp32 math ----
template<int RELU, int ACCUM, class TIN, class TW, class TOUT>
__global__ __launch_bounds__(256) void k_gemm(
    const TIN* __restrict__ IN,                        // [B][K][S]
    const TW* __restrict__ W, long long wsb,           // [M][K], +b*wsb
    const TW* __restrict__ bias, long long bsb,        // [M], +b*bsb
    TOUT* __restrict__ OUT,                            // [B][M][S]
    int M, int K, int S){
  __shared__ float Wl[16][68];   // [k][o]
  __shared__ float Pl[16][64];   // [k][s]
  int b  = blockIdx.z;
  int o0 = blockIdx.y*64;
  int s0 = blockIdx.x*64;
  const TW*  Wb  = W  + (size_t)b*wsb;
  const TIN* INb = IN + (size_t)b*K*S;
  const TW*  Bb  = bias + (size_t)b*bsb;
  int tid = threadIdx.x;
  int ts = tid & 15, to = tid >> 4;
  float acc[4][4] = {};
  for (int k0 = 0; k0 < K; k0 += 16){
    #pragma unroll
    for (int u = 0; u < 4; u++){
      int idx = tid + u*256;
      int o = idx >> 4, k = idx & 15;
      int og = o0 + o;
      Wl[k][o] = (og < M) ? ldf(Wb, (size_t)og*K + k0 + k) : 0.f;
      int k2 = idx >> 6, s2 = idx & 63;
      Pl[k2][s2] = ldf(INb, (size_t)(k0+k2)*S + s0 + s2);
    }
    __syncthreads();
    #pragma unroll
    for (int kk = 0; kk < 16; kk++){
      float4 av = *reinterpret_cast<const float4*>(&Wl[kk][to*4]);
      float4 bv = *reinterpret_cast<const float4*>(&Pl[kk][ts*4]);
      float af[4] = {av.x, av.y, av.z, av.w};
      float bf[4] = {bv.x, bv.y, bv.z, bv.w};
      #pragma unroll
      for (int i = 0; i < 4; i++)
        #pragma unroll
        for (int j = 0; j < 4; j++)
          acc[i][j] += af[i]*bf[j];
    }
    __syncthreads();
  }
  #pragma unroll
  for (int i = 0; i < 4; i++){
    int og = o0 + to*4 + i;
    if (og >= M) continue;
    float bv_ = ldf(Bb, og);
    #pragma unroll
    for (int j = 0; j < 4; j++){
      float v = acc[i][j] + bv_;
      if (RELU) v = fmaxf(v, 0.f);
      size_t oi = ((size_t)b*M + og)*S + s0 + ts*4 + j;
      if (ACCUM) v += ldf(OUT, oi);
      stf(OUT, oi, v);
    }
  }
}

// ------- hypernet GEMM: hk[b][k] = hyp_b[k] + sum_j latcT[j][b]*hyp_w[k][j] (fp32 out) -------
__global__ __launch_bounds__(256) void k_hyper(const float* __restrict__ hw,
    const float* __restrict__ hb, const float* __restrict__ latcT,
    float* __restrict__ hk){
  __shared__ float Wl[32][132];   // [j][k]
  __shared__ float Ll[32][16];    // [j][b]
  __shared__ float Sw[16][132];
  int k0 = blockIdx.x*128;
  int tid = threadIdx.x;
  int tx = tid & 15, ty = tid >> 4;
  float acc[8] = {};
  for (int j0 = 0; j0 < 512; j0 += 32){
    #pragma unroll
    for (int u = 0; u < 16; u++){
      int idx = tid + u*256;
      int k = idx >> 5, j = idx & 31;
      Wl[j][k] = hw[(size_t)(k0+k)*512 + j0 + j];
    }
    {
      int j = tid >> 4, bb = tid & 15;
      Ll[j][bb] = latcT[(j0+j)*16 + bb];
      int idx2 = tid + 256; int j2 = idx2 >> 4, b2 = idx2 & 15;
      Ll[j2][b2] = latcT[(j0+j2)*16 + b2];
    }
    __syncthreads();
    #pragma unroll
    for (int jj = 0; jj < 32; jj++){
      float lv = Ll[jj][tx];
      float4 wa = *reinterpret_cast<const float4*>(&Wl[jj][ty*8]);
      float4 wb = *reinterpret_cast<const float4*>(&Wl[jj][ty*8+4]);
      acc[0]+=wa.x*lv; acc[1]+=wa.y*lv; acc[2]+=wa.z*lv; acc[3]+=wa.w*lv;
      acc[4]+=wb.x*lv; acc[5]+=wb.y*lv; acc[6]+=wb.z*lv; acc[7]+=wb.w*lv;
    }
    __syncthreads();
  }
  #pragma unroll
  for (int i = 0; i < 8; i++) Sw[tx][ty*8+i] = acc[i];
  __syncthreads();
  #pragma unroll
  for (int u = 0; u < 8; u++){
    int idx = tid + u*256;
    int bb = idx >> 7, k = idx & 127;
    hk[(size_t)bb*KHK + k0 + k] = Sw[bb][k] + hb[k0+k];
  }
}

// ---------------- gated residual update (OUT fp32, F fp32) ----------------
__global__ __launch_bounds__(256) void k_update(float* __restrict__ out,
    const float* __restrict__ F, const float* __restrict__ leakp, int S){
  int idx = blockIdx.x*256 + threadIdx.x;
  int s = idx % S;
  int c = (idx / S) & 127;
  int b = idx / (S*128);
  float leak = fminf(fmaxf(leakp[0], 0.001f), 1000.f);
  float a = F[((size_t)b*256 + c)*S + s];
  float g = F[((size_t)b*256 + 128 + c)*S + s];
  out[idx] += leak * a * (1.f / (1.f + expf(-g)));
}

// ---------------- gaussian blur (fp32 -> fp32) ----------------
__global__ __launch_bounds__(256) void k_blur(const float* __restrict__ src,
    float* __restrict__ dst, int H, int W){
  const float G0 = 0.27406862f, G1 = 0.45186276f;
  int S = H*W;
  int idx = blockIdx.x*256 + threadIdx.x;
  int s = idx % S; int bc = idx / S;
  int y = s / W, x = s - y*W;
  const float* sb = src + (size_t)bc*S;
  float g[3] = {G0, G1, G0};
  float acc = 0.f;
  #pragma unroll
  for (int dy = 0; dy < 3; dy++)
    #pragma unroll
    for (int dx = 0; dx < 3; dx++){
      int yy = y + dy - 1, xx = x + dx - 1;
      float v = (yy>=0 && yy<H && xx>=0 && xx<W) ? sb[yy*W+xx] : 0.f;
      acc += v * g[dy] * g[dx];
    }
  dst[idx] = acc;
}

// ---------------- 2x2 mean pool (fp32 -> fp32) ----------------
__global__ __launch_bounds__(256) void k_pool(const float* __restrict__ src,
    float* __restrict__ dst, int H2){
  int S2 = H2*H2;
  int idx = blockIdx.x*256 + threadIdx.x;
  int s = idx % S2;
  int bc = idx / S2;
  int y = s / H2, x = s - y*H2;
  int Ws = H2*2;
  const float* sb = src + (size_t)bc*(4*S2);
  dst[idx] = 0.25f*( sb[(2*y)*Ws + 2*x] + sb[(2*y)*Ws + 2*x + 1]
                   + sb[(2*y+1)*Ws + 2*x] + sb[(2*y+1)*Ws + 2*x + 1]);
}

// ---------------- add seed (broadcast over batch) ----------------
__global__ __launch_bounds__(256) void k_seed(float* __restrict__ out,
    const float* __restrict__ seed){
  int idx = blockIdx.x*256 + threadIdx.x;   // 16*128*256
  out[idx] += seed[idx & 32767];
}

// ---------------- build cs (16,4480) from head output (16,385,256) fp32 ----------------
__global__ __launch_bounds__(256) void k_build_cs(const float* __restrict__ O,
    float* __restrict__ cs){
  int b = blockIdx.x;
  const float* Ob = O + (size_t)b*385*256;
  for (int id = threadIdx.x; id < 4480; id += 256){
    float v;
    if (id < 128){
      const float* p = Ob + id*256; float s = 0;
      for (int t = 0; t < 256; t++) s += p[t];
      v = s * (1.f/256.f);
    } else if (id < 2176){
      int r = id - 128; int c = r >> 4, h = r & 15;
      const float* p = Ob + (128+c)*256 + h*16; float s = 0;
      for (int w = 0; w < 16; w++) s += p[w];
      v = s * (1.f/16.f);
    } else if (id < 4224){
      int r = id - 2176; int c = r >> 4, w = r & 15;
      const float* p = Ob + (256+c)*256 + w; float s = 0;
      for (int h = 0; h < 16; h++) s += p[h*16];
      v = s * (1.f/16.f);
    } else {
      v = Ob[384*256 + (id - 4224)];
    }
    cs[b*4480 + id] = v;
  }
}

// ---------------- small 16-row GEMM: one wave per output row of W ----------------
template<int RELU, int ACCUM, int TRANSOUT>
__global__ __launch_bounds__(256) void k_rowgemm(const float* __restrict__ IN, // [16][K]
    const float* __restrict__ W,    // [M][K]
    const float* __restrict__ bias, // [M]
    float* __restrict__ OUT, int M, int K){
  int wave = (int)((blockIdx.x*256 + threadIdx.x) >> 6);
  int lane = threadIdx.x & 63;
  if (wave >= M) return;
  const float* wr = W + (size_t)wave*K;
  float acc[16] = {};
  for (int k = lane; k < K; k += 64){
    float wv = wr[k];
    #pragma unroll
    for (int b = 0; b < 16; b++) acc[b] += wv * IN[b*K + k];
  }
  #pragma unroll
  for (int b = 0; b < 16; b++)
    for (int off = 32; off > 0; off >>= 1) acc[b] += __shfl_down(acc[b], off);
  if (lane == 0){
    float bv = bias[wave];
    #pragma unroll
    for (int b = 0; b < 16; b++){
      float v = acc[b] + bv;
      if (RELU) v = fmaxf(v, 0.f);
      size_t oi = TRANSOUT ? ((size_t)wave*16 + b) : ((size_t)b*M + wave);
      if (ACCUM) OUT[oi] += v; else OUT[oi] = v;
    }
  }
}

extern "C" void kernel_launch(void* const* d_in, const int* in_sizes, int n_in,
                              void* d_out, int out_size, void* d_ws, size_t ws_size,
                              hipStream_t stream){
  (void)in_sizes; (void)n_in; (void)out_size; (void)ws_size;
  const float* x      = (const float*)d_in[0];
  const float* inj    = (const float*)d_in[1];
  const float* leakp  = (const float*)d_in[2];
  const float* in_w   = (const float*)d_in[3];
  const float* in_b   = (const float*)d_in[4];
  const float* fc_w1  = (const float*)d_in[5];
  const float* fc_b1  = (const float*)d_in[6];
  const float* fc_w2  = (const float*)d_in[7];
  const float* fc_b2  = (const float*)d_in[8];
  const float* fc_wsc = (const float*)d_in[9];
  const float* fc_bsc = (const float*)d_in[10];
  const float* hyp_w  = (const float*)d_in[11];
  const float* hyp_b  = (const float*)d_in[12];
  const float* lat_w  = (const float*)d_in[13];
  const float* lat_b  = (const float*)d_in[14];
  const float* seed   = (const float*)d_in[15];
  const float* out_w  = (const float*)d_in[16];
  const float* out_b  = (const float*)d_in[17];
  const float* l1_w1  = (const float*)d_in[18];
  const float* l1_b1  = (const float*)d_in[19];
  const float* l1_w2  = (const float*)d_in[20];
  const float* l1_b2  = (const float*)d_in[21];
  const float* l1_wsc = (const float*)d_in[22];
  const float* l1_bsc = (const float*)d_in[23];
  const float* l2_w1  = (const float*)d_in[24];
  const float* l2_b1  = (const float*)d_in[25];
  const float* l2_w2  = (const float*)d_in[26];
  const float* l2_b2  = (const float*)d_in[27];
  const float* l2_wsc = (const float*)d_in[28];
  const float* l2_bsc = (const float*)d_in[29];
  const float* fin_w  = (const float*)d_in[30];
  const float* fin_b  = (const float*)d_in[31];

  char* ws = (char*)d_ws;
  float* OUT  = (float*)(ws);                      // 32 MB  fp32 [16][128][S]
  bf16*  P    = (bf16*)(ws + 33554432UL);          // 48 MB  bf16 [16][384][S]
  bf16*  H1   = (bf16*)(ws + 83886080UL);          // 16 MB  bf16 [16][128][S]
  bf16*  H2   = (bf16*)(ws + 100663296UL);         // 16 MB  bf16 [16][128][S]
  float* F    = (float*)(ws + 117440512UL);        // 64 MB  fp32 [16][256][S] (+ temps)
  float* HK   = (float*)(ws + 184549376UL);        // 12.6MB fp32 [16][197376]
  float* LATCT= (float*)(ws + 197181440UL);        // 393 KB [12][512][16]
  float* CS   = (float*)(ws + 197574656UL);        // 287 KB [16][4480]
  float* T1   = (float*)(ws + 197861376UL);        // 64 KB  [16][1024]
  float* HCS  = (float*)(ws + 197926912UL);        // 32 KB
  float* HCS2 = (float*)(ws + 197959680UL);        // 32 KB

  k_in_conv<<<32768, 256, 0, stream>>>(x, in_w, in_b, OUT);

  for (int c = 0; c < 12; c++)
    k_rowgemm<0,0,1><<<128, 256, 0, stream>>>(inj, lat_w + (size_t)c*512*512,
                                              lat_b + c*512, LATCT + c*512*16, 512, 512);

  int H = 64;
  for (int c = 0; c < 12; c++){
    int S = H*H;
    int nEl = 16*128*S;
    k_sobel<<<nEl/256, 256, 0, stream>>>(OUT, P, H, H);
    k_instnorm<<<16*384, 256, 0, stream>>>(P, S);
    dim3 g1(S/64, 2, 16);   // M=128
    dim3 g2(S/64, 4, 16);   // M=256
    k_gemm<1,0,bf16,float,bf16><<<g1, 256, 0, stream>>>(P,  fc_w1,  0, fc_b1,  0, H1, 128, 384, S);
    k_gemm<0,0,bf16,float,float><<<g2, 256, 0, stream>>>(P,  fc_wsc, 0, fc_bsc, 0, F,  256, 384, S);
    k_gemm<0,1,bf16,float,float><<<g2, 256, 0, stream>>>(H1, fc_w2,  0, fc_b2,  0, F,  256, 128, S);
    k_hyper<<<1542, 256, 0, stream>>>(hyp_w, hyp_b, LATCT + (size_t)c*512*16, HK);
    k_gemm<1,0,bf16,float,bf16><<<g1, 256, 0, stream>>>(P,  HK+OFF_WIN, KHK, HK+OFF_BIN, KHK, H1, 128, 384, S);
    k_gemm<1,0,bf16,float,bf16><<<g1, 256, 0, stream>>>(H1, HK+OFF_WMD, KHK, HK+OFF_BMD, KHK, H2, 128, 128, S);
    k_gemm<0,1,bf16,float,float><<<g2, 256, 0, stream>>>(P,  HK+OFF_WSC, KHK, HK+OFF_BSC, KHK, F,  256, 384, S);
    k_gemm<0,1,bf16,float,float><<<g2, 256, 0, stream>>>(H2, HK+OFF_WOT, KHK, HK+OFF_BOT, KHK, F,  256, 128, S);
    k_update<<<nEl/256, 256, 0, stream>>>(OUT, F, leakp, S);
    if (c == 3 || c == 7){
      k_blur<<<nEl/256, 256, 0, stream>>>(OUT, F, H, H);
      int Hn = H/2;
      int n2 = 16*128*Hn*Hn;
      k_pool<<<n2/256, 256, 0, stream>>>(F, OUT, Hn);
      H = Hn;
    }
  }

  k_seed<<<(16*128*256)/256, 256, 0, stream>>>(OUT, seed);
  dim3 gh(4, 7, 16);
  k_gemm<0,0,float,float,float><<<gh, 256, 0, stream>>>(OUT, out_w, 0, out_b, 0, F, 385, 128, 256);
  k_build_cs<<<16, 256, 0, stream>>>(F, CS);

  k_rowgemm<1,0,0><<<256, 256, 0, stream>>>(CS,  l1_w1,  l1_b1,  T1,   1024, 4480);
  k_rowgemm<0,0,0><<<128, 256, 0, stream>>>(CS,  l1_wsc, l1_bsc, HCS,  512, 4480);
  k_rowgemm<0,1,0><<<128, 256, 0, stream>>>(T1,  l1_w2,  l1_b2,  HCS,  512, 1024);
  k_rowgemm<1,0,0><<<128, 256, 0, stream>>>(HCS, l2_w1,  l2_b1,  T1,   512, 512);
  k_rowgemm<0,0,0><<<128, 256, 0, stream>>>(HCS, l2_wsc, l2_bsc, HCS2, 512, 512);
  k_rowgemm<0,1,0><<<128, 256, 0, stream>>>(T1,  l2_w2,  l2_b2,  HCS2, 512, 512);
  // final: fp32 straight into d_out — the reference's output dtype is float32
  k_rowgemm<0,0,0><<<128, 256, 0, stream>>>(HCS2, fin_w, fin_b, (float*)d_out, 512, 512);
}

// Round 5
// 2533.650 us; speedup vs baseline: 3.0415x; 3.0415x over previous
//
#include <hip/hip_runtime.h>
#include <hip/hip_bf16.h>

typedef __hip_bfloat16 bf16;
typedef __attribute__((ext_vector_type(8))) short bf8_t;   // 8 bf16 = 4 VGPR
typedef __attribute__((ext_vector_type(4))) float f4_t;

#define KHK 197376
#define OFF_WIN 0
#define OFF_BIN 49152
#define OFF_WMD 49280
#define OFF_BMD 65664
#define OFF_WOT 65792
#define OFF_BOT 98560
#define OFF_WSC 98816
#define OFF_BSC 197120

__device__ __forceinline__ float ldf(const float* p, size_t i){ return p[i]; }
__device__ __forceinline__ float ldf(const bf16* p, size_t i){ return __bfloat162float(p[i]); }
__device__ __forceinline__ void stf(float* p, size_t i, float v){ p[i] = v; }
__device__ __forceinline__ void stf(bf16* p, size_t i, float v){ p[i] = __float2bfloat16(v); }
__device__ __forceinline__ float b2f(short u){ return __uint_as_float(((unsigned)(unsigned short)u) << 16); }

struct Seg { const bf16* p; int klen; int ld; };

// ---------------- fp32 -> bf16 bulk convert (16B stores) ----------------
__global__ __launch_bounds__(256) void k_cvt_bf16(const float* __restrict__ in,
    bf16* __restrict__ out, size_t n){
  size_t stride = (size_t)gridDim.x * 256;
  for (size_t i = blockIdx.x*256ULL + threadIdx.x; i*8 < n; i += stride){
    float4 a = *reinterpret_cast<const float4*>(in + i*8);
    float4 c = *reinterpret_cast<const float4*>(in + i*8 + 4);
    union { bf8_t v; bf16 e[8]; } o;
    o.e[0]=__float2bfloat16(a.x); o.e[1]=__float2bfloat16(a.y);
    o.e[2]=__float2bfloat16(a.z); o.e[3]=__float2bfloat16(a.w);
    o.e[4]=__float2bfloat16(c.x); o.e[5]=__float2bfloat16(c.y);
    o.e[6]=__float2bfloat16(c.z); o.e[7]=__float2bfloat16(c.w);
    *reinterpret_cast<bf8_t*>(out + i*8) = o.v;
  }
}

// ---------------- input 1x1 conv, channel-last out [b][s][128] ----------------
__global__ __launch_bounds__(256) void k_in_conv(const float* __restrict__ x,
    const float* __restrict__ w, const float* __restrict__ b, float* __restrict__ out){
  int idx = blockIdx.x*256 + threadIdx.x;          // 16*4096*128
  int c = idx & 127;
  int s = (idx >> 7) & 4095;
  int bi = idx >> 19;
  const float* xb = x + (size_t)bi*3*4096;
  out[idx] = b[c] + w[c*3]*xb[s] + w[c*3+1]*xb[4096+s] + w[c*3+2]*xb[8192+s];
}

// ---------------- sobel + concat, channel-last: OUT[b][s][128] -> P[b][s][384] bf16 (raw) ----
__global__ __launch_bounds__(256) void k_sobel(const float* __restrict__ src,
    bf16* __restrict__ p, int H, int S){
  int idx = blockIdx.x*256 + threadIdx.x;          // 16*S*128
  int c = idx & 127;
  int s = (idx >> 7) % S;
  int b = idx / (S*128);
  int y = s / H, x = s - y*H;
  const float* sb = src + (size_t)b*S*128 + c;
  float n[3][3];
  #pragma unroll
  for (int dy=0; dy<3; dy++)
    #pragma unroll
    for (int dx=0; dx<3; dx++){
      int yy = y + dy - 1, xx = x + dx - 1;
      n[dy][dx] = (yy>=0 && yy<H && xx>=0 && xx<H) ? sb[(size_t)(yy*H+xx)*128] : 0.f;
    }
  float sx = (-n[0][0] + n[0][2] - 2.f*n[1][0] + 2.f*n[1][2] - n[2][0] + n[2][2]) * 0.125f;
  float sy = (-n[0][0] - 2.f*n[0][1] - n[0][2] + n[2][0] + 2.f*n[2][1] + n[2][2]) * 0.125f;
  bf16* pb = p + ((size_t)b*S + s)*384;
  pb[c]     = __float2bfloat16(n[1][1]);
  pb[128+c] = __float2bfloat16(sx);
  pb[256+c] = __float2bfloat16(sy);
}

// ---------------- per-(b,c) sums over s of P: SUMS[b][384][2] (pre-zeroed) ----------------
__global__ __launch_bounds__(256) void k_stats(const bf16* __restrict__ P_,
    float* __restrict__ SUMS, int S){
  __shared__ float sS[384], sQ[384];
  int b = blockIdx.y;
  int chunk = S >> 4;
  int s0 = blockIdx.x * chunk;
  int t = threadIdx.x;
  for (int i = t; i < 384; i += 256){ sS[i] = 0.f; sQ[i] = 0.f; }
  __syncthreads();
  if (t < 240){
    int oct = t % 48, ls = t / 48;
    int c8 = oct*8;
    float as[8] = {}, qs[8] = {};
    for (int s = s0 + ls; s < s0 + chunk; s += 5){
      bf8_t v = *reinterpret_cast<const bf8_t*>(P_ + ((size_t)b*S + s)*384 + c8);
      #pragma unroll
      for (int i=0;i<8;i++){ float f = b2f(v[i]); as[i]+=f; qs[i]+=f*f; }
    }
    #pragma unroll
    for (int i=0;i<8;i++){ atomicAdd(&sS[c8+i], as[i]); atomicAdd(&sQ[c8+i], qs[i]); }
  }
  __syncthreads();
  for (int i = t; i < 384; i += 256){
    atomicAdd(&SUMS[((size_t)b*384+i)*2],   sS[i]);
    atomicAdd(&SUMS[((size_t)b*384+i)*2+1], sQ[i]);
  }
}

__global__ __launch_bounds__(256) void k_finstats(const float* __restrict__ SUMS,
    float* __restrict__ MEAN, float* __restrict__ INVS, float Sf, int n){
  int i = blockIdx.x*256 + threadIdx.x;
  if (i < n){
    float m = SUMS[i*2] / Sf;
    float var = SUMS[i*2+1] / Sf - m*m;
    MEAN[i] = m;
    INVS[i] = rsqrtf(fmaxf(var, 0.f) + 1e-5f);
  }
}

// ---------------- hypernet GEMM via MFMA: hk[b][197376] = hb + hwb·latb^T ----------------
__global__ __launch_bounds__(256) void k_hyper_mfma(const bf16* __restrict__ hwb,
    const float* __restrict__ hb, const bf16* __restrict__ latb,   // latb [16][512]
    float* __restrict__ hk){
  __shared__ float Sw[128][17];
  int h0 = blockIdx.x * 128;
  int tid = threadIdx.x, wid = tid >> 6, lane = tid & 63;
  int lr = lane & 15, lg = lane >> 4;
  f4_t acc[2] = {{}};
  const bf16* la = latb + (size_t)lr * 512;
  #pragma unroll 4
  for (int k0 = 0; k0 < 512; k0 += 32){
    bf8_t bv = *reinterpret_cast<const bf8_t*>(la + k0 + lg*8);
    #pragma unroll
    for (int f = 0; f < 2; f++){
      int h = h0 + wid*32 + f*16 + lr;
      bf8_t av = *reinterpret_cast<const bf8_t*>(hwb + (size_t)h*512 + k0 + lg*8);
      acc[f] = __builtin_amdgcn_mfma_f32_16x16x32_bf16(av, bv, acc[f], 0, 0, 0);
    }
  }
  #pragma unroll
  for (int f = 0; f < 2; f++)
    #pragma unroll
    for (int r = 0; r < 4; r++)
      Sw[wid*32 + f*16 + lg*4 + r][lr] = acc[f][r];
  __syncthreads();
  int bb = tid >> 4, h8 = (tid & 15) * 8;
  #pragma unroll
  for (int i = 0; i < 8; i++)
    hk[(size_t)bb*KHK + h0 + h8 + i] = hb[h0 + h8 + i] + Sw[h8 + i][bb];
}

// ---------------- weight transform: fold instnorm into weights, build stacked mats ----------
__global__ __launch_bounds__(256) void k_xform(
    const float* __restrict__ fc_w1, const float* __restrict__ fc_b1,
    const float* __restrict__ fc_w2, const float* __restrict__ fc_b2,
    const float* __restrict__ fc_wsc, const float* __restrict__ fc_bsc,
    const float* __restrict__ HK_, const float* __restrict__ MEAN,
    const float* __restrict__ INVS,
    bf16* __restrict__ Wstack, float* __restrict__ bstack,
    bf16* __restrict__ Wbig, float* __restrict__ bbig,
    bf16* __restrict__ Wmd, float* __restrict__ bmd){
  int gw = (blockIdx.x*256 + threadIdx.x) >> 6;
  int lane = threadIdx.x & 63;
  if (gw < 4096){                     // Wstack rows: [fc_w1 ; w_in] per batch
    int b = gw >> 8, o = gw & 255;
    const float* mv = MEAN + b*384; const float* iv = INVS + b*384;
    const float* src; float b0;
    if (o < 128){ src = fc_w1 + (size_t)o*384; b0 = fc_b1[o]; }
    else { src = HK_ + (size_t)b*KHK + OFF_WIN + (size_t)(o-128)*384;
           b0 = HK_[(size_t)b*KHK + OFF_BIN + (o-128)]; }
    float accv = 0.f;
    bf16* dst = Wstack + ((size_t)b*256 + o)*384;
    for (int k = lane; k < 384; k += 64){
      float w = src[k] * iv[k];
      accv += w * mv[k];
      dst[k] = __float2bfloat16(w);
    }
    for (int off=32; off>0; off>>=1) accv += __shfl_down(accv, off);
    if (lane==0) bstack[b*256+o] = b0 - accv;
  } else if (gw < 8192){              // Wbig rows: [fc_wsc+w_sc | fc_w2 | w_ot]
    int r = gw - 4096; int b = r >> 8, o = r & 255;
    const float* mv = MEAN + b*384; const float* iv = INVS + b*384;
    const float* hkb = HK_ + (size_t)b*KHK;
    bf16* dst = Wbig + ((size_t)b*256 + o)*640;
    float accv = 0.f;
    for (int k = lane; k < 384; k += 64){
      float w = (fc_wsc[(size_t)o*384 + k] + hkb[OFF_WSC + (size_t)o*384 + k]) * iv[k];
      accv += w * mv[k];
      dst[k] = __float2bfloat16(w);
    }
    for (int k = lane; k < 128; k += 64){
      dst[384+k] = __float2bfloat16(fc_w2[(size_t)o*128 + k]);
      dst[512+k] = __float2bfloat16(hkb[OFF_WOT + (size_t)o*128 + k]);
    }
    for (int off=32; off>0; off>>=1) accv += __shfl_down(accv, off);
    if (lane==0) bbig[b*256+o] = fc_bsc[o] + hkb[OFF_BSC+o] + fc_b2[o] + hkb[OFF_BOT+o] - accv;
  } else {                            // Wmd rows
    int r = gw - 8192; int b = r >> 7, o = r & 127;
    const float* hkb = HK_ + (size_t)b*KHK;
    bf16* dst = Wmd + ((size_t)b*128 + o)*128;
    for (int k = lane; k < 128; k += 64)
      dst[k] = __float2bfloat16(hkb[OFF_WMD + (size_t)o*128 + k]);
    if (lane==0) bmd[b*128+o] = hkb[OFF_BMD + o];
  }
}

// ---------------- MFMA GEMM: OUT[b][s][n] = act(bias + sum_seg IN[b][s][k]·W[n][k]) --------
template<int RELU, int NSEG, class TOUT>
__global__ __launch_bounds__(256) void k_mfgemm(
    Seg s1, Seg s2, Seg s3,
    const bf16* __restrict__ W, long long wbstride, int Ktot,
    const float* __restrict__ bias, int bbstride,
    TOUT* __restrict__ OUTp, int ldc, int Mout, int S){
  __shared__ short As[128][40];
  __shared__ short Bs[128][40];
  int b  = blockIdx.z;
  int s0 = blockIdx.x * 128;
  int n0 = blockIdx.y * 128;
  int tid = threadIdx.x;
  int wid = tid >> 6, lane = tid & 63;
  int wrow = (wid >> 1) * 64;     // wave s-offset
  int wcol = (wid & 1) * 64;      // wave n-offset
  int lr = lane & 15, lg = lane >> 4;
  int srow = tid >> 2, sq = (tid & 3) * 8;
  const bf16* Wb = W + (size_t)b * wbstride;
  f4_t acc[4][4] = {{}};
  int kbase = 0;
  #pragma unroll
  for (int si = 0; si < NSEG; si++){
    Seg sg = (si == 0) ? s1 : (si == 1) ? s2 : s3;
    const bf16* INb = sg.p + (size_t)b * S * sg.ld;
    for (int k0 = 0; k0 < sg.klen; k0 += 32){
      const bf16* srcA = INb + (size_t)(s0 + srow) * sg.ld + k0 + sq;
      *(bf8_t*)(&As[srow][sq])      = *(const bf8_t*)srcA;
      *(bf8_t*)(&As[srow+64][sq])   = *(const bf8_t*)(srcA + (size_t)64 * sg.ld);
      int kw = kbase + k0 + sq;
      int n = n0 + srow;
      bf8_t v0 = (bf8_t)(short)0, v1 = (bf8_t)(short)0;
      if (n < Mout)      v0 = *(const bf8_t*)(Wb + (size_t)n * Ktot + kw);
      if (n + 64 < Mout) v1 = *(const bf8_t*)(Wb + (size_t)(n+64) * Ktot + kw);
      *(bf8_t*)(&Bs[srow][sq])    = v0;
      *(bf8_t*)(&Bs[srow+64][sq]) = v1;
      __syncthreads();
      bf8_t af[4], bfv[4];
      #pragma unroll
      for (int i = 0; i < 4; i++) af[i]  = *(const bf8_t*)(&As[wrow + i*16 + lr][lg*8]);
      #pragma unroll
      for (int j = 0; j < 4; j++) bfv[j] = *(const bf8_t*)(&Bs[wcol + j*16 + lr][lg*8]);
      #pragma unroll
      for (int i = 0; i < 4; i++)
        #pragma unroll
        for (int j = 0; j < 4; j++)
          acc[i][j] = __builtin_amdgcn_mfma_f32_16x16x32_bf16(af[i], bfv[j], acc[i][j], 0, 0, 0);
      __syncthreads();
    }
    kbase += sg.klen;
  }
  #pragma unroll
  for (int j = 0; j < 4; j++){
    int n = n0 + wcol + j*16 + lr;
    if (n >= Mout) continue;
    float bv = bias[(size_t)b * bbstride + n];
    #pragma unroll
    for (int i = 0; i < 4; i++){
      int sr = s0 + wrow + i*16 + lg*4;
      size_t base = ((size_t)b * S + sr) * ldc + n;
      #pragma unroll
      for (int r = 0; r < 4; r++){
        float v = acc[i][j][r] + bv;
        if (RELU) v = fmaxf(v, 0.f);
        stf(OUTp, base + (size_t)r * ldc, v);
      }
    }
  }
}

// ---------------- gated residual update, channel-last ----------------
__global__ __launch_bounds__(256) void k_update(float* __restrict__ out,
    const float* __restrict__ F, const float* __restrict__ leakp, int S){
  int idx = blockIdx.x*256 + threadIdx.x;   // 16*S*128
  int c = idx & 127;
  size_t r = (size_t)(idx >> 7);            // b*S + s
  float leak = fminf(fmaxf(leakp[0], 0.001f), 1000.f);
  float a = F[r*256 + c];
  float g = F[r*256 + 128 + c];
  out[idx] += leak * a * (1.f / (1.f + expf(-g)));
}

// ---------------- gaussian blur channel-last ----------------
__global__ __launch_bounds__(256) void k_blur(const float* __restrict__ src,
    float* __restrict__ dst, int H, int S){
  const float G0 = 0.27406862f, G1 = 0.45186276f;
  int idx = blockIdx.x*256 + threadIdx.x;
  int c = idx & 127;
  int s = (idx >> 7) % S;
  int b = idx / (S*128);
  int y = s / H, x = s - y*H;
  const float* sb = src + (size_t)b*S*128 + c;
  float g[3] = {G0, G1, G0};
  float acc = 0.f;
  #pragma unroll
  for (int dy = 0; dy < 3; dy++)
    #pragma unroll
    for (int dx = 0; dx < 3; dx++){
      int yy = y + dy - 1, xx = x + dx - 1;
      float v = (yy>=0 && yy<H && xx>=0 && xx<H) ? sb[(size_t)(yy*H+xx)*128] : 0.f;
      acc += v * g[dy] * g[dx];
    }
  dst[idx] = acc;
}

// ---------------- 2x2 mean pool channel-last ----------------
__global__ __launch_bounds__(256) void k_pool(const float* __restrict__ src,
    float* __restrict__ dst, int H2, int S2){
  int idx = blockIdx.x*256 + threadIdx.x;   // 16*S2*128
  int c = idx & 127;
  int s2 = (idx >> 7) % S2;
  int b = idx / (S2*128);
  int y = s2 / H2, x = s2 - y*H2;
  int W = H2*2;
  const float* sb = src + (size_t)b*(4*S2)*128 + c;
  dst[idx] = 0.25f*( sb[(size_t)((2*y)*W + 2*x)*128]   + sb[(size_t)((2*y)*W + 2*x+1)*128]
                   + sb[(size_t)((2*y+1)*W + 2*x)*128] + sb[(size_t)((2*y+1)*W + 2*x+1)*128]);
}

// ---------------- add seed (seed is channel-first [128][256]) ----------------
__global__ __launch_bounds__(256) void k_seed(float* __restrict__ out,
    const float* __restrict__ seed){
  int idx = blockIdx.x*256 + threadIdx.x;   // 16*256*128
  int c = idx & 127;
  int s = (idx >> 7) & 255;
  out[idx] += seed[c*256 + s];
}

// ---------------- build cs (16,4480) from Ohead [16][256][385] ----------------
__global__ __launch_bounds__(256) void k_build_cs(const float* __restrict__ O,
    float* __restrict__ cs){
  int b = blockIdx.x;
  const float* Ob = O + (size_t)b*256*385;
  for (int id = threadIdx.x; id < 4480; id += 256){
    float v;
    if (id < 128){
      float s = 0; for (int t = 0; t < 256; t++) s += Ob[(size_t)t*385 + id];
      v = s * (1.f/256.f);
    } else if (id < 2176){
      int r = id - 128; int c = r >> 4, h = r & 15;
      float s = 0; for (int w = 0; w < 16; w++) s += Ob[(size_t)(h*16+w)*385 + 128 + c];
      v = s * (1.f/16.f);
    } else if (id < 4224){
      int r = id - 2176; int c = r >> 4, w = r & 15;
      float s = 0; for (int h = 0; h < 16; h++) s += Ob[(size_t)(h*16+w)*385 + 256 + c];
      v = s * (1.f/16.f);
    } else {
      v = Ob[(size_t)(id - 4224)*385 + 384];
    }
    cs[b*4480 + id] = v;
  }
}

// ---------------- small 16-row GEMM: one wave per output row of W ----------------
template<int RELU, int ACCUM, class TOUT>
__global__ __launch_bounds__(256) void k_rowgemm(const float* __restrict__ IN, // [16][K]
    const float* __restrict__ W,    // [M][K]
    const float* __restrict__ bias, // [M]
    TOUT* __restrict__ OUT, int M, int K){
  int wave = (int)((blockIdx.x*256 + threadIdx.x) >> 6);
  int lane = threadIdx.x & 63;
  if (wave >= M) return;
  const float* wr = W + (size_t)wave*K;
  float acc[16] = {};
  for (int k = lane; k < K; k += 64){
    float wv = wr[k];
    #pragma unroll
    for (int b = 0; b < 16; b++) acc[b] += wv * IN[b*K + k];
  }
  #pragma unroll
  for (int b = 0; b < 16; b++)
    for (int off = 32; off > 0; off >>= 1) acc[b] += __shfl_down(acc[b], off);
  if (lane == 0){
    float bv = bias[wave];
    #pragma unroll
    for (int b = 0; b < 16; b++){
      float v = acc[b] + bv;
      if (RELU) v = fmaxf(v, 0.f);
      size_t oi = (size_t)b*M + wave;
      if (ACCUM) v += ldf(OUT, oi);
      stf(OUT, oi, v);
    }
  }
}

extern "C" void kernel_launch(void* const* d_in, const int* in_sizes, int n_in,
                              void* d_out, int out_size, void* d_ws, size_t ws_size,
                              hipStream_t stream){
  (void)in_sizes; (void)n_in; (void)out_size; (void)ws_size;
  const float* x      = (const float*)d_in[0];
  const float* inj    = (const float*)d_in[1];
  const float* leakp  = (const float*)d_in[2];
  const float* in_w   = (const float*)d_in[3];
  const float* in_b   = (const float*)d_in[4];
  const float* fc_w1  = (const float*)d_in[5];
  const float* fc_b1  = (const float*)d_in[6];
  const float* fc_w2  = (const float*)d_in[7];
  const float* fc_b2  = (const float*)d_in[8];
  const float* fc_wsc = (const float*)d_in[9];
  const float* fc_bsc = (const float*)d_in[10];
  const float* hyp_w  = (const float*)d_in[11];
  const float* hyp_b  = (const float*)d_in[12];
  const float* lat_w  = (const float*)d_in[13];
  const float* lat_b  = (const float*)d_in[14];
  const float* seed   = (const float*)d_in[15];
  const float* out_w  = (const float*)d_in[16];
  const float* out_b  = (const float*)d_in[17];
  const float* l1_w1  = (const float*)d_in[18];
  const float* l1_b1  = (const float*)d_in[19];
  const float* l1_w2  = (const float*)d_in[20];
  const float* l1_b2  = (const float*)d_in[21];
  const float* l1_wsc = (const float*)d_in[22];
  const float* l1_bsc = (const float*)d_in[23];
  const float* l2_w1  = (const float*)d_in[24];
  const float* l2_b1  = (const float*)d_in[25];
  const float* l2_w2  = (const float*)d_in[26];
  const float* l2_b2  = (const float*)d_in[27];
  const float* l2_wsc = (const float*)d_in[28];
  const float* l2_bsc = (const float*)d_in[29];
  const float* fin_w  = (const float*)d_in[30];
  const float* fin_b  = (const float*)d_in[31];

  char* ws = (char*)d_ws;
  float* OUT   = (float*)(ws);                       // 32MB  [16][4096][128] fp32 (channel-last)
  bf16*  P     = (bf16*)(ws + 33554432UL);           // 48MB  [16][4096][384]
  bf16*  HG    = (bf16*)(ws + 83886080UL);           // 32MB  [16][4096][256]  (H1 | G1)
  bf16*  G2    = (bf16*)(ws + 117440512UL);          // 16MB  [16][4096][128]
  float* F     = (float*)(ws + 134217728UL);         // 64MB  [16][4096][256] fp32 (+blur tmp)
  bf16*  HWB   = (bf16*)(ws + 201326592UL);          // 202MB hyp_w bf16 [197376][512]
  float* HK    = (float*)(ws + 411041792UL);         // 12.6MB [16][197376]
  bf16*  WSTK  = (bf16*)(ws + 423673856UL);          // 3.1MB [16][256][384]
  bf16*  WBIG  = (bf16*)(ws + 426819584UL);          // 5.2MB [16][256][640]
  bf16*  WMD   = (bf16*)(ws + 432062464UL);          // 512KB [16][128][128]
  float* BSTK  = (float*)(ws + 432586752UL);         // [16][256]
  float* BBIG  = (float*)(ws + 432603136UL);         // [16][256]
  float* BMD   = (float*)(ws + 432619520UL);         // [16][128]
  float* MEAN  = (float*)(ws + 432627712UL);         // [16][384]
  float* INVS  = (float*)(ws + 432652288UL);         // [16][384]
  float* SUMS  = (float*)(ws + 432676864UL);         // [16][384][2]
  bf16*  LATB  = (bf16*)(ws + 432726016UL);          // [12][16][512]
  bf16*  OUTB  = (bf16*)(ws + 432922624UL);          // [16][256][128]
  float* OHEAD = (float*)(ws + 433971200UL);         // [16][256][385]
  bf16*  OWB   = (bf16*)(ws + 440279040UL);          // [385][128]
  float* CS    = (float*)(ws + 440377600UL);         // [16][4480]
  float* T1    = (float*)(ws + 440664320UL);         // [16][1024]
  float* HCS   = (float*)(ws + 440729856UL);         // [16][512]
  float* HCS2  = (float*)(ws + 440762624UL);         // [16][512]

  k_cvt_bf16<<<4096, 256, 0, stream>>>(hyp_w, HWB, 101056512ULL);
  k_cvt_bf16<<<32, 256, 0, stream>>>(out_w, OWB, 49280ULL);
  k_in_conv<<<32768, 256, 0, stream>>>(x, in_w, in_b, OUT);

  for (int c = 0; c < 12; c++)
    k_rowgemm<0,0,bf16><<<128, 256, 0, stream>>>(inj, lat_w + (size_t)c*512*512,
                                                 lat_b + c*512, LATB + c*8192, 512, 512);

  int H = 64;
  for (int c = 0; c < 12; c++){
    int S = H*H;
    int nEl = 16*S*128;
    k_sobel<<<nEl/256, 256, 0, stream>>>(OUT, P, H, S);
    hipMemsetAsync(SUMS, 0, 16*384*2*sizeof(float), stream);
    k_stats<<<dim3(16,16), 256, 0, stream>>>(P, SUMS, S);
    k_finstats<<<24, 256, 0, stream>>>(SUMS, MEAN, INVS, (float)S, 6144);
    k_hyper_mfma<<<1542, 256, 0, stream>>>(HWB, hyp_b, LATB + c*8192, HK);
    k_xform<<<2560, 256, 0, stream>>>(fc_w1, fc_b1, fc_w2, fc_b2, fc_wsc, fc_bsc,
                                      HK, MEAN, INVS, WSTK, BSTK, WBIG, BBIG, WMD, BMD);
    Seg segP  = {P, 384, 384};
    Seg segH1 = {HG, 128, 256};
    Seg segHm = {HG + 128, 128, 256};
    Seg segG2 = {G2, 128, 128};
    k_mfgemm<1,1,bf16><<<dim3(S/128, 2, 16), 256, 0, stream>>>(
        segP, segP, segP, WSTK, 98304LL, 384, BSTK, 256, HG, 256, 256, S);
    k_mfgemm<1,1,bf16><<<dim3(S/128, 1, 16), 256, 0, stream>>>(
        segHm, segHm, segHm, WMD, 16384LL, 128, BMD, 128, G2, 128, 128, S);
    k_mfgemm<0,3,float><<<dim3(S/128, 2, 16), 256, 0, stream>>>(
        segP, segH1, segG2, WBIG, 163840LL, 640, BBIG, 256, F, 256, 256, S);
    k_update<<<nEl/256, 256, 0, stream>>>(OUT, F, leakp, S);
    if (c == 3 || c == 7){
      k_blur<<<nEl/256, 256, 0, stream>>>(OUT, F, H, S);
      int H2 = H/2, S2 = S/4;
      k_pool<<<(16*S2*128)/256, 256, 0, stream>>>(F, OUT, H2, S2);
      H = H2;
    }
  }

  k_seed<<<2048, 256, 0, stream>>>(OUT, seed);
  k_cvt_bf16<<<256, 256, 0, stream>>>(OUT, OUTB, 524288ULL);
  Seg segO = {OUTB, 128, 128};
  k_mfgemm<0,1,float><<<dim3(2, 4, 16), 256, 0, stream>>>(
      segO, segO, segO, OWB, 0LL, 128, out_b, 0, OHEAD, 385, 385, 256);
  k_build_cs<<<16, 256, 0, stream>>>(OHEAD, CS);

  k_rowgemm<1,0,float><<<256, 256, 0, stream>>>(CS,  l1_w1,  l1_b1,  T1,   1024, 4480);
  k_rowgemm<0,0,float><<<128, 256, 0, stream>>>(CS,  l1_wsc, l1_bsc, HCS,  512, 4480);
  k_rowgemm<0,1,float><<<128, 256, 0, stream>>>(T1,  l1_w2,  l1_b2,  HCS,  512, 1024);
  k_rowgemm<1,0,float><<<128, 256, 0, stream>>>(HCS, l2_w1,  l2_b1,  T1,   512, 512);
  k_rowgemm<0,0,float><<<128, 256, 0, stream>>>(HCS, l2_wsc, l2_bsc, HCS2, 512, 512);
  k_rowgemm<0,1,float><<<128, 256, 0, stream>>>(T1,  l2_w2,  l2_b2,  HCS2, 512, 512);
  k_rowgemm<0,0,float><<<128, 256, 0, stream>>>(HCS2, fin_w, fin_b, (float*)d_out, 512, 512);
}

// Round 6
// 1917.102 us; speedup vs baseline: 4.0196x; 1.3216x over previous
//
#include <hip/hip_runtime.h>
#include <hip/hip_bf16.h>

typedef __hip_bfloat16 bf16;
typedef __attribute__((ext_vector_type(8))) short bf8_t;   // 8 bf16 = 4 VGPR
typedef __attribute__((ext_vector_type(4))) float f4_t;

#define KHK 197376
#define OFF_WIN 0
#define OFF_BIN 49152
#define OFF_WMD 49280
#define OFF_BMD 65664
#define OFF_WOT 65792
#define OFF_BOT 98560
#define OFF_WSC 98816
#define OFF_BSC 197120

__device__ __forceinline__ float ldf(const float* p, size_t i){ return p[i]; }
__device__ __forceinline__ float ldf(const bf16* p, size_t i){ return __bfloat162float(p[i]); }
__device__ __forceinline__ void stf(float* p, size_t i, float v){ p[i] = v; }
__device__ __forceinline__ void stf(bf16* p, size_t i, float v){ p[i] = __float2bfloat16(v); }
__device__ __forceinline__ float b2f(short u){ return __uint_as_float(((unsigned)(unsigned short)u) << 16); }

struct Seg { const bf16* p; int klen; int ld; };

// ---------------- fp32 -> bf16 bulk convert (16B stores) ----------------
__global__ __launch_bounds__(256) void k_cvt_bf16(const float* __restrict__ in,
    bf16* __restrict__ out, size_t n){
  size_t stride = (size_t)gridDim.x * 256;
  for (size_t i = blockIdx.x*256ULL + threadIdx.x; i*8 < n; i += stride){
    float4 a = *reinterpret_cast<const float4*>(in + i*8);
    float4 c = *reinterpret_cast<const float4*>(in + i*8 + 4);
    union { bf8_t v; bf16 e[8]; } o;
    o.e[0]=__float2bfloat16(a.x); o.e[1]=__float2bfloat16(a.y);
    o.e[2]=__float2bfloat16(a.z); o.e[3]=__float2bfloat16(a.w);
    o.e[4]=__float2bfloat16(c.x); o.e[5]=__float2bfloat16(c.y);
    o.e[6]=__float2bfloat16(c.z); o.e[7]=__float2bfloat16(c.w);
    *reinterpret_cast<bf8_t*>(out + i*8) = o.v;
  }
}

// ---------------- input 1x1 conv, channel-last out [b][s][128] ----------------
__global__ __launch_bounds__(256) void k_in_conv(const float* __restrict__ x,
    const float* __restrict__ w, const float* __restrict__ b, float* __restrict__ out){
  int idx = blockIdx.x*256 + threadIdx.x;          // 16*4096*128
  int c = idx & 127;
  int s = (idx >> 7) & 4095;
  int bi = idx >> 19;
  const float* xb = x + (size_t)bi*3*4096;
  out[idx] = b[c] + w[c*3]*xb[s] + w[c*3+1]*xb[4096+s] + w[c*3+2]*xb[8192+s];
}

// ---------------- sobel + concat, channel-last: OUT[b][s][128] -> P[b][s][384] bf16 (raw) ----
__global__ __launch_bounds__(256) void k_sobel(const float* __restrict__ src,
    bf16* __restrict__ p, int H, int S){
  int idx = blockIdx.x*256 + threadIdx.x;          // 16*S*128
  int c = idx & 127;
  int s = (idx >> 7) % S;
  int b = idx / (S*128);
  int y = s / H, x = s - y*H;
  const float* sb = src + (size_t)b*S*128 + c;
  float n[3][3];
  #pragma unroll
  for (int dy=0; dy<3; dy++)
    #pragma unroll
    for (int dx=0; dx<3; dx++){
      int yy = y + dy - 1, xx = x + dx - 1;
      n[dy][dx] = (yy>=0 && yy<H && xx>=0 && xx<H) ? sb[(size_t)(yy*H+xx)*128] : 0.f;
    }
  float sx = (-n[0][0] + n[0][2] - 2.f*n[1][0] + 2.f*n[1][2] - n[2][0] + n[2][2]) * 0.125f;
  float sy = (-n[0][0] - 2.f*n[0][1] - n[0][2] + n[2][0] + 2.f*n[2][1] + n[2][2]) * 0.125f;
  bf16* pb = p + ((size_t)b*S + s)*384;
  pb[c]     = __float2bfloat16(n[1][1]);
  pb[128+c] = __float2bfloat16(sx);
  pb[256+c] = __float2bfloat16(sy);
}

// ---------------- per-(b,c) sums over s of P: SUMS[b][384][2] (pre-zeroed) ----------------
__global__ __launch_bounds__(256) void k_stats(const bf16* __restrict__ P_,
    float* __restrict__ SUMS, int S){
  __shared__ float sS[384], sQ[384];
  int b = blockIdx.y;
  int chunk = S >> 4;
  int s0 = blockIdx.x * chunk;
  int t = threadIdx.x;
  for (int i = t; i < 384; i += 256){ sS[i] = 0.f; sQ[i] = 0.f; }
  __syncthreads();
  if (t < 240){
    int oct = t % 48, ls = t / 48;
    int c8 = oct*8;
    float as[8] = {}, qs[8] = {};
    for (int s = s0 + ls; s < s0 + chunk; s += 5){
      bf8_t v = *reinterpret_cast<const bf8_t*>(P_ + ((size_t)b*S + s)*384 + c8);
      #pragma unroll
      for (int i=0;i<8;i++){ float f = b2f(v[i]); as[i]+=f; qs[i]+=f*f; }
    }
    #pragma unroll
    for (int i=0;i<8;i++){ atomicAdd(&sS[c8+i], as[i]); atomicAdd(&sQ[c8+i], qs[i]); }
  }
  __syncthreads();
  for (int i = t; i < 384; i += 256){
    atomicAdd(&SUMS[((size_t)b*384+i)*2],   sS[i]);
    atomicAdd(&SUMS[((size_t)b*384+i)*2+1], sQ[i]);
  }
}

// ------- batched hypernet: hk_all[c][b][197376] for ALL 12 cells, one pass over hyp_w -------
__global__ __launch_bounds__(256) void k_hyper_all(const float* __restrict__ hw,
    const float* __restrict__ hb, const bf16* __restrict__ latb,   // [12*16][512]
    float* __restrict__ hk_all){                                   // [12][16][KHK]
  __shared__ float Sw[128][17];
  int h0 = blockIdx.x * 128;
  int tid = threadIdx.x, wid = tid >> 6, lane = tid & 63;
  int lr = lane & 15, lg = lane >> 4;
  f4_t acc[2][12];
  #pragma unroll
  for (int f=0; f<2; f++)
    #pragma unroll
    for (int j=0; j<12; j++) acc[f][j] = (f4_t){0.f,0.f,0.f,0.f};
  for (int k0 = 0; k0 < 512; k0 += 32){
    bf8_t af[2];
    #pragma unroll
    for (int f = 0; f < 2; f++){
      int h = h0 + wid*32 + f*16 + lr;
      const float* src = hw + (size_t)h*512 + k0 + lg*8;
      float4 x0 = *reinterpret_cast<const float4*>(src);
      float4 x1 = *reinterpret_cast<const float4*>(src + 4);
      union { bf8_t v; bf16 e[8]; } o;
      o.e[0]=__float2bfloat16(x0.x); o.e[1]=__float2bfloat16(x0.y);
      o.e[2]=__float2bfloat16(x0.z); o.e[3]=__float2bfloat16(x0.w);
      o.e[4]=__float2bfloat16(x1.x); o.e[5]=__float2bfloat16(x1.y);
      o.e[6]=__float2bfloat16(x1.z); o.e[7]=__float2bfloat16(x1.w);
      af[f] = o.v;
    }
    #pragma unroll
    for (int j = 0; j < 12; j++){
      bf8_t bv = *reinterpret_cast<const bf8_t*>(latb + (size_t)(j*16 + lr)*512 + k0 + lg*8);
      acc[0][j] = __builtin_amdgcn_mfma_f32_16x16x32_bf16(af[0], bv, acc[0][j], 0, 0, 0);
      acc[1][j] = __builtin_amdgcn_mfma_f32_16x16x32_bf16(af[1], bv, acc[1][j], 0, 0, 0);
    }
  }
  for (int j = 0; j < 12; j++){
    __syncthreads();
    #pragma unroll
    for (int f = 0; f < 2; f++)
      #pragma unroll
      for (int r = 0; r < 4; r++)
        Sw[wid*32 + f*16 + lg*4 + r][lr] = acc[f][j][r];
    __syncthreads();
    int bb = tid >> 4, h8 = (tid & 15) * 8;
    #pragma unroll
    for (int i = 0; i < 8; i++)
      hk_all[((size_t)j*16 + bb)*KHK + h0 + h8 + i] = hb[h0 + h8 + i] + Sw[h8 + i][bb];
  }
}

// ------ weight transform: fold instnorm into weights, build stacked mats, a/g interleave ----
__global__ __launch_bounds__(256) void k_xform(
    const float* __restrict__ fc_w1, const float* __restrict__ fc_b1,
    const float* __restrict__ fc_w2, const float* __restrict__ fc_b2,
    const float* __restrict__ fc_wsc, const float* __restrict__ fc_bsc,
    const float* __restrict__ HK_, const float* __restrict__ SUMS, float Sf,
    bf16* __restrict__ Wstack, float* __restrict__ bstack,
    bf16* __restrict__ Wbig, float* __restrict__ bbig,
    bf16* __restrict__ Wmd, float* __restrict__ bmd){
  int gw = (blockIdx.x*256 + threadIdx.x) >> 6;
  int lane = threadIdx.x & 63;
  float invSf = 1.f / Sf;
  if (gw < 4096){                     // Wstack rows: [fc_w1 ; w_in] per batch
    int b = gw >> 8, o = gw & 255;
    const float* su = SUMS + (size_t)b*768;
    const float* src; float b0;
    if (o < 128){ src = fc_w1 + (size_t)o*384; b0 = fc_b1[o]; }
    else { src = HK_ + (size_t)b*KHK + OFF_WIN + (size_t)(o-128)*384;
           b0 = HK_[(size_t)b*KHK + OFF_BIN + (o-128)]; }
    float accv = 0.f;
    bf16* dst = Wstack + ((size_t)b*256 + o)*384;
    for (int k = lane; k < 384; k += 64){
      float m = su[k*2] * invSf;
      float iv = rsqrtf(fmaxf(su[k*2+1]*invSf - m*m, 0.f) + 1e-5f);
      float w = src[k] * iv;
      accv += w * m;
      dst[k] = __float2bfloat16(w);
    }
    for (int off=32; off>0; off>>=1) accv += __shfl_down(accv, off);
    if (lane==0) bstack[b*256+o] = b0 - accv;
  } else if (gw < 8192){              // Wbig rows: [fc_wsc+w_sc | fc_w2 | w_ot], a/g interleave
    int r = gw - 4096; int b = r >> 8, o = r & 255;
    const float* su = SUMS + (size_t)b*768;
    const float* hkb = HK_ + (size_t)b*KHK;
    int cc = o & 127;
    int nr = ((cc >> 4) << 5) + ((o >> 7) << 4) + (cc & 15);   // 16-row a/g interleave
    bf16* dst = Wbig + ((size_t)b*256 + nr)*640;
    float accv = 0.f;
    for (int k = lane; k < 384; k += 64){
      float m = su[k*2] * invSf;
      float iv = rsqrtf(fmaxf(su[k*2+1]*invSf - m*m, 0.f) + 1e-5f);
      float w = (fc_wsc[(size_t)o*384 + k] + hkb[OFF_WSC + (size_t)o*384 + k]) * iv;
      accv += w * m;
      dst[k] = __float2bfloat16(w);
    }
    for (int k = lane; k < 128; k += 64){
      dst[384+k] = __float2bfloat16(fc_w2[(size_t)o*128 + k]);
      dst[512+k] = __float2bfloat16(hkb[OFF_WOT + (size_t)o*128 + k]);
    }
    for (int off=32; off>0; off>>=1) accv += __shfl_down(accv, off);
    if (lane==0) bbig[b*256+nr] = fc_bsc[o] + hkb[OFF_BSC+o] + fc_b2[o] + hkb[OFF_BOT+o] - accv;
  } else {                            // Wmd rows
    int r = gw - 8192; int b = r >> 7, o = r & 127;
    const float* hkb = HK_ + (size_t)b*KHK;
    bf16* dst = Wmd + ((size_t)b*128 + o)*128;
    for (int k = lane; k < 128; k += 64)
      dst[k] = __float2bfloat16(hkb[OFF_WMD + (size_t)o*128 + k]);
    if (lane==0) bmd[b*128+o] = hkb[OFF_BMD + o];
  }
}

// ------ MFMA GEMM. FUSE=1: interleaved a/g cols, epilogue does OUT += leak*a*sigmoid(g) ------
template<int RELU, int NSEG, int FUSE, class TOUT>
__global__ __launch_bounds__(256) void k_mfgemm(
    Seg s1, Seg s2, Seg s3,
    const bf16* __restrict__ W, long long wbstride, int Ktot,
    const float* __restrict__ bias, int bbstride,
    TOUT* __restrict__ OUTp, int ldc, int Mout, int S,
    const float* __restrict__ leakp){
  __shared__ short As[128][40];
  __shared__ short Bs[128][40];
  int b  = blockIdx.z;
  int s0 = blockIdx.x * 128;
  int n0 = blockIdx.y * 128;
  int tid = threadIdx.x;
  int wid = tid >> 6, lane = tid & 63;
  int wrow = (wid >> 1) * 64;     // wave s-offset
  int wcol = (wid & 1) * 64;      // wave n-offset
  int lr = lane & 15, lg = lane >> 4;
  int srow = tid >> 2, sq = (tid & 3) * 8;
  const bf16* Wb = W + (size_t)b * wbstride;
  f4_t acc[4][4] = {{}};
  int kbase = 0;
  #pragma unroll
  for (int si = 0; si < NSEG; si++){
    Seg sg = (si == 0) ? s1 : (si == 1) ? s2 : s3;
    const bf16* INb = sg.p + (size_t)b * S * sg.ld;
    for (int k0 = 0; k0 < sg.klen; k0 += 32){
      const bf16* srcA = INb + (size_t)(s0 + srow) * sg.ld + k0 + sq;
      *(bf8_t*)(&As[srow][sq])      = *(const bf8_t*)srcA;
      *(bf8_t*)(&As[srow+64][sq])   = *(const bf8_t*)(srcA + (size_t)64 * sg.ld);
      int kw = kbase + k0 + sq;
      int n = n0 + srow;
      bf8_t v0 = (bf8_t)(short)0, v1 = (bf8_t)(short)0;
      if (n < Mout)      v0 = *(const bf8_t*)(Wb + (size_t)n * Ktot + kw);
      if (n + 64 < Mout) v1 = *(const bf8_t*)(Wb + (size_t)(n+64) * Ktot + kw);
      *(bf8_t*)(&Bs[srow][sq])    = v0;
      *(bf8_t*)(&Bs[srow+64][sq]) = v1;
      __syncthreads();
      bf8_t af[4], bfv[4];
      #pragma unroll
      for (int i = 0; i < 4; i++) af[i]  = *(const bf8_t*)(&As[wrow + i*16 + lr][lg*8]);
      #pragma unroll
      for (int j = 0; j < 4; j++) bfv[j] = *(const bf8_t*)(&Bs[wcol + j*16 + lr][lg*8]);
      #pragma unroll
      for (int i = 0; i < 4; i++)
        #pragma unroll
        for (int j = 0; j < 4; j++)
          acc[i][j] = __builtin_amdgcn_mfma_f32_16x16x32_bf16(af[i], bfv[j], acc[i][j], 0, 0, 0);
      __syncthreads();
    }
    kbase += sg.klen;
  }
  if (FUSE){
    float leak = fminf(fmaxf(leakp[0], 0.001f), 1000.f);
    float* OUTf = (float*)OUTp;
    #pragma unroll
    for (int jp = 0; jp < 2; jp++){
      int na = n0 + wcol + jp*32 + lr;
      float bva = bias[(size_t)b * bbstride + na];
      float bvg = bias[(size_t)b * bbstride + na + 16];
      int chan = ((n0 + wcol) >> 1) + jp*16 + lr;
      #pragma unroll
      for (int i = 0; i < 4; i++){
        int sr = s0 + wrow + i*16 + lg*4;
        #pragma unroll
        for (int r = 0; r < 4; r++){
          float av = acc[i][jp*2][r]   + bva;
          float gv = acc[i][jp*2+1][r] + bvg;
          size_t oidx = ((size_t)b * S + sr + r) * 128 + chan;
          OUTf[oidx] += leak * av * (1.f / (1.f + expf(-gv)));
        }
      }
    }
  } else {
    #pragma unroll
    for (int j = 0; j < 4; j++){
      int n = n0 + wcol + j*16 + lr;
      if (n >= Mout) continue;
      float bv = bias[(size_t)b * bbstride + n];
      #pragma unroll
      for (int i = 0; i < 4; i++){
        int sr = s0 + wrow + i*16 + lg*4;
        size_t base = ((size_t)b * S + sr) * ldc + n;
        #pragma unroll
        for (int r = 0; r < 4; r++){
          float v = acc[i][j][r] + bv;
          if (RELU) v = fmaxf(v, 0.f);
          stf(OUTp, base + (size_t)r * ldc, v);
        }
      }
    }
  }
}

// ---------------- gaussian blur channel-last ----------------
__global__ __launch_bounds__(256) void k_blur(const float* __restrict__ src,
    float* __restrict__ dst, int H, int S){
  const float G0 = 0.27406862f, G1 = 0.45186276f;
  int idx = blockIdx.x*256 + threadIdx.x;
  int c = idx & 127;
  int s = (idx >> 7) % S;
  int b = idx / (S*128);
  int y = s / H, x = s - y*H;
  const float* sb = src + (size_t)b*S*128 + c;
  float g[3] = {G0, G1, G0};
  float acc = 0.f;
  #pragma unroll
  for (int dy = 0; dy < 3; dy++)
    #pragma unroll
    for (int dx = 0; dx < 3; dx++){
      int yy = y + dy - 1, xx = x + dx - 1;
      float v = (yy>=0 && yy<H && xx>=0 && xx<H) ? sb[(size_t)(yy*H+xx)*128] : 0.f;
      acc += v * g[dy] * g[dx];
    }
  dst[idx] = acc;
}

// ---------------- 2x2 mean pool channel-last ----------------
__global__ __launch_bounds__(256) void k_pool(const float* __restrict__ src,
    float* __restrict__ dst, int H2, int S2){
  int idx = blockIdx.x*256 + threadIdx.x;   // 16*S2*128
  int c = idx & 127;
  int s2 = (idx >> 7) % S2;
  int b = idx / (S2*128);
  int y = s2 / H2, x = s2 - y*H2;
  int W = H2*2;
  const float* sb = src + (size_t)b*(4*S2)*128 + c;
  dst[idx] = 0.25f*( sb[(size_t)((2*y)*W + 2*x)*128]   + sb[(size_t)((2*y)*W + 2*x+1)*128]
                   + sb[(size_t)((2*y+1)*W + 2*x)*128] + sb[(size_t)((2*y+1)*W + 2*x+1)*128]);
}

// ---------------- add seed (seed is channel-first [128][256]) ----------------
__global__ __launch_bounds__(256) void k_seed(float* __restrict__ out,
    const float* __restrict__ seed){
  int idx = blockIdx.x*256 + threadIdx.x;   // 16*256*128
  int c = idx & 127;
  int s = (idx >> 7) & 255;
  out[idx] += seed[c*256 + s];
}

// ---------------- build cs (16,4480) from Ohead [16][256][385] ----------------
__global__ __launch_bounds__(256) void k_build_cs(const float* __restrict__ O,
    float* __restrict__ cs){
  int b = blockIdx.x;
  const float* Ob = O + (size_t)b*256*385;
  for (int id = threadIdx.x; id < 4480; id += 256){
    float v;
    if (id < 128){
      float s = 0; for (int t = 0; t < 256; t++) s += Ob[(size_t)t*385 + id];
      v = s * (1.f/256.f);
    } else if (id < 2176){
      int r = id - 128; int c = r >> 4, h = r & 15;
      float s = 0; for (int w = 0; w < 16; w++) s += Ob[(size_t)(h*16+w)*385 + 128 + c];
      v = s * (1.f/16.f);
    } else if (id < 4224){
      int r = id - 2176; int c = r >> 4, w = r & 15;
      float s = 0; for (int h = 0; h < 16; h++) s += Ob[(size_t)(h*16+w)*385 + 256 + c];
      v = s * (1.f/16.f);
    } else {
      v = Ob[(size_t)(id - 4224)*385 + 384];
    }
    cs[b*4480 + id] = v;
  }
}

// ---------------- small 16-row GEMM: one wave per output row of W ----------------
template<int RELU, int ACCUM, class TOUT>
__global__ __launch_bounds__(256) void k_rowgemm(const float* __restrict__ IN, // [16][K]
    const float* __restrict__ W,    // [M][K]
    const float* __restrict__ bias, // [M]
    TOUT* __restrict__ OUT, int M, int K){
  int wave = (int)((blockIdx.x*256 + threadIdx.x) >> 6);
  int lane = threadIdx.x & 63;
  if (wave >= M) return;
  const float* wr = W + (size_t)wave*K;
  float acc[16] = {};
  for (int k = lane; k < K; k += 64){
    float wv = wr[k];
    #pragma unroll
    for (int b = 0; b < 16; b++) acc[b] += wv * IN[b*K + k];
  }
  #pragma unroll
  for (int b = 0; b < 16; b++)
    for (int off = 32; off > 0; off >>= 1) acc[b] += __shfl_down(acc[b], off);
  if (lane == 0){
    float bv = bias[wave];
    #pragma unroll
    for (int b = 0; b < 16; b++){
      float v = acc[b] + bv;
      if (RELU) v = fmaxf(v, 0.f);
      size_t oi = (size_t)b*M + wave;
      if (ACCUM) v += ldf(OUT, oi);
      stf(OUT, oi, v);
    }
  }
}

extern "C" void kernel_launch(void* const* d_in, const int* in_sizes, int n_in,
                              void* d_out, int out_size, void* d_ws, size_t ws_size,
                              hipStream_t stream){
  (void)in_sizes; (void)n_in; (void)out_size; (void)ws_size;
  const float* x      = (const float*)d_in[0];
  const float* inj    = (const float*)d_in[1];
  const float* leakp  = (const float*)d_in[2];
  const float* in_w   = (const float*)d_in[3];
  const float* in_b   = (const float*)d_in[4];
  const float* fc_w1  = (const float*)d_in[5];
  const float* fc_b1  = (const float*)d_in[6];
  const float* fc_w2  = (const float*)d_in[7];
  const float* fc_b2  = (const float*)d_in[8];
  const float* fc_wsc = (const float*)d_in[9];
  const float* fc_bsc = (const float*)d_in[10];
  const float* hyp_w  = (const float*)d_in[11];
  const float* hyp_b  = (const float*)d_in[12];
  const float* lat_w  = (const float*)d_in[13];
  const float* lat_b  = (const float*)d_in[14];
  const float* seed   = (const float*)d_in[15];
  const float* out_w  = (const float*)d_in[16];
  const float* out_b  = (const float*)d_in[17];
  const float* l1_w1  = (const float*)d_in[18];
  const float* l1_b1  = (const float*)d_in[19];
  const float* l1_w2  = (const float*)d_in[20];
  const float* l1_b2  = (const float*)d_in[21];
  const float* l1_wsc = (const float*)d_in[22];
  const float* l1_bsc = (const float*)d_in[23];
  const float* l2_w1  = (const float*)d_in[24];
  const float* l2_b1  = (const float*)d_in[25];
  const float* l2_w2  = (const float*)d_in[26];
  const float* l2_b2  = (const float*)d_in[27];
  const float* l2_wsc = (const float*)d_in[28];
  const float* l2_bsc = (const float*)d_in[29];
  const float* fin_w  = (const float*)d_in[30];
  const float* fin_b  = (const float*)d_in[31];

  char* ws = (char*)d_ws;
  float* OUT    = (float*)(ws);                      // 32MB  [16][4096][128] fp32
  bf16*  P      = (bf16*)(ws + 33554432UL);          // 48MB  [16][4096][384] (+blur tmp)
  bf16*  HG     = (bf16*)(ws + 83886080UL);          // 32MB  [16][4096][256]
  bf16*  G2     = (bf16*)(ws + 117440512UL);         // 16MB  [16][4096][128]
  float* HKALL  = (float*)(ws + 134217728UL);        // 151.6MB [12][16][197376]
  bf16*  WSTK   = (bf16*)(ws + 285802496UL);         // 3.1MB [16][256][384]
  bf16*  WBIG   = (bf16*)(ws + 288948224UL);         // 5.2MB [16][256][640]
  bf16*  WMD    = (bf16*)(ws + 294191104UL);         // 512KB [16][128][128]
  float* BSTK   = (float*)(ws + 294715392UL);        // [16][256]
  float* BBIG   = (float*)(ws + 294731776UL);        // [16][256]
  float* BMD    = (float*)(ws + 294748160UL);        // [16][128]
  float* SUMS   = (float*)(ws + 294756352UL);        // [16][384][2]
  bf16*  LATB   = (bf16*)(ws + 294805504UL);         // [12][16][512]
  bf16*  OUTB   = (bf16*)(ws + 295002112UL);         // [16][256][128]
  float* OHEAD  = (float*)(ws + 296050688UL);        // [16][256][385]
  bf16*  OWB    = (bf16*)(ws + 302358528UL);         // [385][128]
  float* CS     = (float*)(ws + 302457088UL);        // [16][4480]
  float* T1     = (float*)(ws + 302743808UL);        // [16][1024]
  float* HCS    = (float*)(ws + 302809344UL);        // [16][512]
  float* HCS2   = (float*)(ws + 302842112UL);        // [16][512]

  k_cvt_bf16<<<32, 256, 0, stream>>>(out_w, OWB, 49280ULL);
  k_in_conv<<<32768, 256, 0, stream>>>(x, in_w, in_b, OUT);

  for (int c = 0; c < 12; c++)
    k_rowgemm<0,0,bf16><<<128, 256, 0, stream>>>(inj, lat_w + (size_t)c*512*512,
                                                 lat_b + c*512, LATB + c*8192, 512, 512);
  // one pass over hyp_w (fp32, converted in-register) computes hk for all 12 cells
  k_hyper_all<<<1542, 256, 0, stream>>>(hyp_w, hyp_b, LATB, HKALL);

  int H = 64;
  for (int c = 0; c < 12; c++){
    int S = H*H;
    int nEl = 16*S*128;
    k_sobel<<<nEl/256, 256, 0, stream>>>(OUT, P, H, S);
    hipMemsetAsync(SUMS, 0, 16*384*2*sizeof(float), stream);
    k_stats<<<dim3(16,16), 256, 0, stream>>>(P, SUMS, S);
    k_xform<<<2560, 256, 0, stream>>>(fc_w1, fc_b1, fc_w2, fc_b2, fc_wsc, fc_bsc,
                                      HKALL + (size_t)c*16*KHK, SUMS, (float)S,
                                      WSTK, BSTK, WBIG, BBIG, WMD, BMD);
    Seg segP  = {P, 384, 384};
    Seg segH1 = {HG, 128, 256};
    Seg segHm = {HG + 128, 128, 256};
    Seg segG2 = {G2, 128, 128};
    k_mfgemm<1,1,0,bf16><<<dim3(S/128, 2, 16), 256, 0, stream>>>(
        segP, segP, segP, WSTK, 98304LL, 384, BSTK, 256, HG, 256, 256, S, nullptr);
    k_mfgemm<1,1,0,bf16><<<dim3(S/128, 1, 16), 256, 0, stream>>>(
        segHm, segHm, segHm, WMD, 16384LL, 128, BMD, 128, G2, 128, 128, S, nullptr);
    // fused: computes d+f (a/g interleaved cols) and applies OUT += leak*a*sigmoid(g)
    k_mfgemm<0,3,1,float><<<dim3(S/128, 2, 16), 256, 0, stream>>>(
        segP, segH1, segG2, WBIG, 163840LL, 640, BBIG, 256, OUT, 128, 256, S, leakp);
    if (c == 3 || c == 7){
      k_blur<<<nEl/256, 256, 0, stream>>>(OUT, (float*)P, H, S);
      int H2 = H/2, S2 = S/4;
      k_pool<<<(16*S2*128)/256, 256, 0, stream>>>((float*)P, OUT, H2, S2);
      H = H2;
    }
  }

  k_seed<<<2048, 256, 0, stream>>>(OUT, seed);
  k_cvt_bf16<<<256, 256, 0, stream>>>(OUT, OUTB, 524288ULL);
  Seg segO = {OUTB, 128, 128};
  k_mfgemm<0,1,0,float><<<dim3(2, 4, 16), 256, 0, stream>>>(
      segO, segO, segO, OWB, 0LL, 128, out_b, 0, OHEAD, 385, 385, 256, nullptr);
  k_build_cs<<<16, 256, 0, stream>>>(OHEAD, CS);

  k_rowgemm<1,0,float><<<256, 256, 0, stream>>>(CS,  l1_w1,  l1_b1,  T1,   1024, 4480);
  k_rowgemm<0,0,float><<<128, 256, 0, stream>>>(CS,  l1_wsc, l1_bsc, HCS,  512, 4480);
  k_rowgemm<0,1,float><<<128, 256, 0, stream>>>(T1,  l1_w2,  l1_b2,  HCS,  512, 1024);
  k_rowgemm<1,0,float><<<128, 256, 0, stream>>>(HCS, l2_w1,  l2_b1,  T1,   512, 512);
  k_rowgemm<0,0,float><<<128, 256, 0, stream>>>(HCS, l2_wsc, l2_bsc, HCS2, 512, 512);
  k_rowgemm<0,1,float><<<128, 256, 0, stream>>>(T1,  l2_w2,  l2_b2,  HCS2, 512, 512);
  k_rowgemm<0,0,float><<<128, 256, 0, stream>>>(HCS2, fin_w, fin_b, (float*)d_out, 512, 512);
}

// Round 7
// 1884.723 us; speedup vs baseline: 4.0887x; 1.0172x over previous
//
#include <hip/hip_runtime.h>
#include <hip/hip_bf16.h>

typedef __hip_bfloat16 bf16;
typedef __attribute__((ext_vector_type(8))) short bf8_t;   // 8 bf16 = 4 VGPR
typedef __attribute__((ext_vector_type(4))) float f4_t;

#define KHK 197376
#define OFF_WIN 0
#define OFF_BIN 49152
#define OFF_WMD 49280
#define OFF_BMD 65664
#define OFF_WOT 65792
#define OFF_BOT 98560
#define OFF_WSC 98816
#define OFF_BSC 197120

__device__ __forceinline__ float ldf(const float* p, size_t i){ return p[i]; }
__device__ __forceinline__ float ldf(const bf16* p, size_t i){ return __bfloat162float(p[i]); }
__device__ __forceinline__ void stf(float* p, size_t i, float v){ p[i] = v; }
__device__ __forceinline__ void stf(bf16* p, size_t i, float v){ p[i] = __float2bfloat16(v); }
__device__ __forceinline__ float b2f(short u){ return __uint_as_float(((unsigned)(unsigned short)u) << 16); }

struct Seg { const bf16* p; int klen; int ld; };

// ---------------- fp32 -> bf16 bulk convert (16B stores) ----------------
__global__ __launch_bounds__(256) void k_cvt_bf16(const float* __restrict__ in,
    bf16* __restrict__ out, size_t n){
  size_t stride = (size_t)gridDim.x * 256;
  for (size_t i = blockIdx.x*256ULL + threadIdx.x; i*8 < n; i += stride){
    float4 a = *reinterpret_cast<const float4*>(in + i*8);
    float4 c = *reinterpret_cast<const float4*>(in + i*8 + 4);
    union { bf8_t v; bf16 e[8]; } o;
    o.e[0]=__float2bfloat16(a.x); o.e[1]=__float2bfloat16(a.y);
    o.e[2]=__float2bfloat16(a.z); o.e[3]=__float2bfloat16(a.w);
    o.e[4]=__float2bfloat16(c.x); o.e[5]=__float2bfloat16(c.y);
    o.e[6]=__float2bfloat16(c.z); o.e[7]=__float2bfloat16(c.w);
    *reinterpret_cast<bf8_t*>(out + i*8) = o.v;
  }
}

// ---------------- input 1x1 conv, channel-last out [b][s][128] ----------------
__global__ __launch_bounds__(256) void k_in_conv(const float* __restrict__ x,
    const float* __restrict__ w, const float* __restrict__ b, float* __restrict__ out){
  int idx = blockIdx.x*256 + threadIdx.x;          // 16*4096*128
  int c = idx & 127;
  int s = (idx >> 7) & 4095;
  int bi = idx >> 19;
  const float* xb = x + (size_t)bi*3*4096;
  out[idx] = b[c] + w[c*3]*xb[s] + w[c*3+1]*xb[4096+s] + w[c*3+2]*xb[8192+s];
}

// ---------------- sobel + concat, channel-last: OUT[b][s][128] -> P[b][s][384] bf16 (raw) ----
__global__ __launch_bounds__(256) void k_sobel(const float* __restrict__ src,
    bf16* __restrict__ p, int H, int S){
  int idx = blockIdx.x*256 + threadIdx.x;          // 16*S*128
  int c = idx & 127;
  int s = (idx >> 7) % S;
  int b = idx / (S*128);
  int y = s / H, x = s - y*H;
  const float* sb = src + (size_t)b*S*128 + c;
  float n[3][3];
  #pragma unroll
  for (int dy=0; dy<3; dy++)
    #pragma unroll
    for (int dx=0; dx<3; dx++){
      int yy = y + dy - 1, xx = x + dx - 1;
      n[dy][dx] = (yy>=0 && yy<H && xx>=0 && xx<H) ? sb[(size_t)(yy*H+xx)*128] : 0.f;
    }
  float sx = (-n[0][0] + n[0][2] - 2.f*n[1][0] + 2.f*n[1][2] - n[2][0] + n[2][2]) * 0.125f;
  float sy = (-n[0][0] - 2.f*n[0][1] - n[0][2] + n[2][0] + 2.f*n[2][1] + n[2][2]) * 0.125f;
  bf16* pb = p + ((size_t)b*S + s)*384;
  pb[c]     = __float2bfloat16(n[1][1]);
  pb[128+c] = __float2bfloat16(sx);
  pb[256+c] = __float2bfloat16(sy);
}

// ---------------- per-(b,c) sums over s of P: SUMS[b][384][2] (pre-zeroed) ----------------
__global__ __launch_bounds__(256) void k_stats(const bf16* __restrict__ P_,
    float* __restrict__ SUMS, int S){
  __shared__ float sS[384], sQ[384];
  int b = blockIdx.y;
  int chunk = S >> 4;
  int s0 = blockIdx.x * chunk;
  int t = threadIdx.x;
  for (int i = t; i < 384; i += 256){ sS[i] = 0.f; sQ[i] = 0.f; }
  __syncthreads();
  if (t < 240){
    int oct = t % 48, ls = t / 48;
    int c8 = oct*8;
    float as[8] = {}, qs[8] = {};
    for (int s = s0 + ls; s < s0 + chunk; s += 5){
      bf8_t v = *reinterpret_cast<const bf8_t*>(P_ + ((size_t)b*S + s)*384 + c8);
      #pragma unroll
      for (int i=0;i<8;i++){ float f = b2f(v[i]); as[i]+=f; qs[i]+=f*f; }
    }
    #pragma unroll
    for (int i=0;i<8;i++){ atomicAdd(&sS[c8+i], as[i]); atomicAdd(&sQ[c8+i], qs[i]); }
  }
  __syncthreads();
  for (int i = t; i < 384; i += 256){
    atomicAdd(&SUMS[((size_t)b*384+i)*2],   sS[i]);
    atomicAdd(&SUMS[((size_t)b*384+i)*2+1], sQ[i]);
  }
}

// ------- batched hypernet v2: coalesced LDS-staged, hk_all[c][b][KHK] for all 12 cells -------
__global__ __launch_bounds__(256) void k_hyper_all(const float* __restrict__ hw,
    const float* __restrict__ hb, const bf16* __restrict__ latb,   // [12*16][512]
    float* __restrict__ hk_all){                                   // [12][16][KHK]
  __shared__ short Wl[2][128][72];     // k-tile: 128 rows x 64 cols (+8 pad)
  __shared__ float Sw[128][17];
  int h0 = blockIdx.x * 128;
  int tid = threadIdx.x, wid = tid >> 6, lane = tid & 63;
  int lr = lane & 15, lg = lane >> 4;
  int strow = tid >> 3, stcol = (tid & 7) * 8;     // staging map: 32 rows/iter
  f4_t acc[2][12];
  #pragma unroll
  for (int f=0; f<2; f++)
    #pragma unroll
    for (int j=0; j<12; j++) acc[f][j] = (f4_t){0.f,0.f,0.f,0.f};

  // stage k-tile kt into buffer buf (coalesced: 8 consecutive floats per lane)
  auto stage = [&](int kt, int buf){
    #pragma unroll
    for (int it = 0; it < 4; it++){
      int row = it*32 + strow;
      const float* src = hw + (size_t)(h0+row)*512 + kt*64 + stcol;
      float4 a = *reinterpret_cast<const float4*>(src);
      float4 c = *reinterpret_cast<const float4*>(src + 4);
      union { bf8_t v; bf16 e[8]; } o;
      o.e[0]=__float2bfloat16(a.x); o.e[1]=__float2bfloat16(a.y);
      o.e[2]=__float2bfloat16(a.z); o.e[3]=__float2bfloat16(a.w);
      o.e[4]=__float2bfloat16(c.x); o.e[5]=__float2bfloat16(c.y);
      o.e[6]=__float2bfloat16(c.z); o.e[7]=__float2bfloat16(c.w);
      *reinterpret_cast<bf8_t*>(&Wl[buf][row][stcol]) = o.v;
    }
  };

  stage(0, 0);
  __syncthreads();
  for (int kt = 0; kt < 8; kt++){
    int cur = kt & 1;
    if (kt < 7) stage(kt+1, cur^1);
    #pragma unroll
    for (int ks = 0; ks < 2; ks++){
      int kk = kt*64 + ks*32;
      bf8_t af[2];
      #pragma unroll
      for (int f = 0; f < 2; f++)
        af[f] = *reinterpret_cast<const bf8_t*>(&Wl[cur][wid*32 + f*16 + lr][ks*32 + lg*8]);
      #pragma unroll
      for (int j = 0; j < 12; j++){
        bf8_t bv = *reinterpret_cast<const bf8_t*>(latb + (size_t)(j*16 + lr)*512 + kk + lg*8);
        acc[0][j] = __builtin_amdgcn_mfma_f32_16x16x32_bf16(af[0], bv, acc[0][j], 0, 0, 0);
        acc[1][j] = __builtin_amdgcn_mfma_f32_16x16x32_bf16(af[1], bv, acc[1][j], 0, 0, 0);
      }
    }
    __syncthreads();
  }

  for (int j = 0; j < 12; j++){
    __syncthreads();
    #pragma unroll
    for (int f = 0; f < 2; f++)
      #pragma unroll
      for (int r = 0; r < 4; r++)
        Sw[wid*32 + f*16 + lg*4 + r][lr] = acc[f][j][r];
    __syncthreads();
    int bb = tid >> 4, h8 = (tid & 15) * 8;
    #pragma unroll
    for (int i = 0; i < 8; i++)
      hk_all[((size_t)j*16 + bb)*KHK + h0 + h8 + i] = hb[h0 + h8 + i] + Sw[h8 + i][bb];
  }
}

// ---------------- all 12 latc GEMMs in one launch: LATB[c][b][512] bf16 ----------------
__global__ __launch_bounds__(256) void k_latall(const float* __restrict__ inj,
    const float* __restrict__ lat_w, const float* __restrict__ lat_b,
    bf16* __restrict__ LATB){
  int gwave = (int)((blockIdx.x*256 + threadIdx.x) >> 6);   // 0..6143
  int lane = threadIdx.x & 63;
  int c = gwave >> 9, o = gwave & 511;
  const float* wr = lat_w + (size_t)c*262144 + (size_t)o*512;
  float acc[16] = {};
  for (int k = lane; k < 512; k += 64){
    float wv = wr[k];
    #pragma unroll
    for (int b = 0; b < 16; b++) acc[b] += wv * inj[b*512 + k];
  }
  #pragma unroll
  for (int b = 0; b < 16; b++)
    for (int off = 32; off > 0; off >>= 1) acc[b] += __shfl_down(acc[b], off);
  if (lane == 0){
    float bv = lat_b[c*512 + o];
    #pragma unroll
    for (int b = 0; b < 16; b++)
      LATB[(size_t)c*8192 + b*512 + o] = __float2bfloat16(acc[b] + bv);
  }
}

// ------ weight transform: fold instnorm into weights, build stacked mats, a/g interleave ----
__global__ __launch_bounds__(256) void k_xform(
    const float* __restrict__ fc_w1, const float* __restrict__ fc_b1,
    const float* __restrict__ fc_w2, const float* __restrict__ fc_b2,
    const float* __restrict__ fc_wsc, const float* __restrict__ fc_bsc,
    const float* __restrict__ HK_, const float* __restrict__ SUMS, float Sf,
    bf16* __restrict__ Wstack, float* __restrict__ bstack,
    bf16* __restrict__ Wbig, float* __restrict__ bbig,
    bf16* __restrict__ Wmd, float* __restrict__ bmd){
  int gw = (blockIdx.x*256 + threadIdx.x) >> 6;
  int lane = threadIdx.x & 63;
  float invSf = 1.f / Sf;
  if (gw < 4096){                     // Wstack rows: [fc_w1 ; w_in] per batch
    int b = gw >> 8, o = gw & 255;
    const float* su = SUMS + (size_t)b*768;
    const float* src; float b0;
    if (o < 128){ src = fc_w1 + (size_t)o*384; b0 = fc_b1[o]; }
    else { src = HK_ + (size_t)b*KHK + OFF_WIN + (size_t)(o-128)*384;
           b0 = HK_[(size_t)b*KHK + OFF_BIN + (o-128)]; }
    float accv = 0.f;
    bf16* dst = Wstack + ((size_t)b*256 + o)*384;
    for (int k = lane; k < 384; k += 64){
      float m = su[k*2] * invSf;
      float iv = rsqrtf(fmaxf(su[k*2+1]*invSf - m*m, 0.f) + 1e-5f);
      float w = src[k] * iv;
      accv += w * m;
      dst[k] = __float2bfloat16(w);
    }
    for (int off=32; off>0; off>>=1) accv += __shfl_down(accv, off);
    if (lane==0) bstack[b*256+o] = b0 - accv;
  } else if (gw < 8192){              // Wbig rows: [fc_wsc+w_sc | fc_w2 | w_ot], a/g interleave
    int r = gw - 4096; int b = r >> 8, o = r & 255;
    const float* su = SUMS + (size_t)b*768;
    const float* hkb = HK_ + (size_t)b*KHK;
    int cc = o & 127;
    int nr = ((cc >> 4) << 5) + ((o >> 7) << 4) + (cc & 15);   // 16-row a/g interleave
    bf16* dst = Wbig + ((size_t)b*256 + nr)*640;
    float accv = 0.f;
    for (int k = lane; k < 384; k += 64){
      float m = su[k*2] * invSf;
      float iv = rsqrtf(fmaxf(su[k*2+1]*invSf - m*m, 0.f) + 1e-5f);
      float w = (fc_wsc[(size_t)o*384 + k] + hkb[OFF_WSC + (size_t)o*384 + k]) * iv;
      accv += w * m;
      dst[k] = __float2bfloat16(w);
    }
    for (int k = lane; k < 128; k += 64){
      dst[384+k] = __float2bfloat16(fc_w2[(size_t)o*128 + k]);
      dst[512+k] = __float2bfloat16(hkb[OFF_WOT + (size_t)o*128 + k]);
    }
    for (int off=32; off>0; off>>=1) accv += __shfl_down(accv, off);
    if (lane==0) bbig[b*256+nr] = fc_bsc[o] + hkb[OFF_BSC+o] + fc_b2[o] + hkb[OFF_BOT+o] - accv;
  } else {                            // Wmd rows
    int r = gw - 8192; int b = r >> 7, o = r & 127;
    const float* hkb = HK_ + (size_t)b*KHK;
    bf16* dst = Wmd + ((size_t)b*128 + o)*128;
    for (int k = lane; k < 128; k += 64)
      dst[k] = __float2bfloat16(hkb[OFF_WMD + (size_t)o*128 + k]);
    if (lane==0) bmd[b*128+o] = hkb[OFF_BMD + o];
  }
}

// ------ MFMA GEMM. FUSE=1: interleaved a/g cols, epilogue does OUT += leak*a*sigmoid(g) ------
template<int RELU, int NSEG, int FUSE, class TOUT>
__global__ __launch_bounds__(256) void k_mfgemm(
    Seg s1, Seg s2, Seg s3,
    const bf16* __restrict__ W, long long wbstride, int Ktot,
    const float* __restrict__ bias, int bbstride,
    TOUT* __restrict__ OUTp, int ldc, int Mout, int S,
    const float* __restrict__ leakp){
  __shared__ short As[128][40];
  __shared__ short Bs[128][40];
  int b  = blockIdx.z;
  int s0 = blockIdx.x * 128;
  int n0 = blockIdx.y * 128;
  int tid = threadIdx.x;
  int wid = tid >> 6, lane = tid & 63;
  int wrow = (wid >> 1) * 64;     // wave s-offset
  int wcol = (wid & 1) * 64;      // wave n-offset
  int lr = lane & 15, lg = lane >> 4;
  int srow = tid >> 2, sq = (tid & 3) * 8;
  const bf16* Wb = W + (size_t)b * wbstride;
  f4_t acc[4][4] = {{}};
  int kbase = 0;
  #pragma unroll
  for (int si = 0; si < NSEG; si++){
    Seg sg = (si == 0) ? s1 : (si == 1) ? s2 : s3;
    const bf16* INb = sg.p + (size_t)b * S * sg.ld;
    for (int k0 = 0; k0 < sg.klen; k0 += 32){
      const bf16* srcA = INb + (size_t)(s0 + srow) * sg.ld + k0 + sq;
      *(bf8_t*)(&As[srow][sq])      = *(const bf8_t*)srcA;
      *(bf8_t*)(&As[srow+64][sq])   = *(const bf8_t*)(srcA + (size_t)64 * sg.ld);
      int kw = kbase + k0 + sq;
      int n = n0 + srow;
      bf8_t v0 = (bf8_t)(short)0, v1 = (bf8_t)(short)0;
      if (n < Mout)      v0 = *(const bf8_t*)(Wb + (size_t)n * Ktot + kw);
      if (n + 64 < Mout) v1 = *(const bf8_t*)(Wb + (size_t)(n+64) * Ktot + kw);
      *(bf8_t*)(&Bs[srow][sq])    = v0;
      *(bf8_t*)(&Bs[srow+64][sq]) = v1;
      __syncthreads();
      bf8_t af[4], bfv[4];
      #pragma unroll
      for (int i = 0; i < 4; i++) af[i]  = *(const bf8_t*)(&As[wrow + i*16 + lr][lg*8]);
      #pragma unroll
      for (int j = 0; j < 4; j++) bfv[j] = *(const bf8_t*)(&Bs[wcol + j*16 + lr][lg*8]);
      #pragma unroll
      for (int i = 0; i < 4; i++)
        #pragma unroll
        for (int j = 0; j < 4; j++)
          acc[i][j] = __builtin_amdgcn_mfma_f32_16x16x32_bf16(af[i], bfv[j], acc[i][j], 0, 0, 0);
      __syncthreads();
    }
    kbase += sg.klen;
  }
  if (FUSE){
    float leak = fminf(fmaxf(leakp[0], 0.001f), 1000.f);
    float* OUTf = (float*)OUTp;
    #pragma unroll
    for (int jp = 0; jp < 2; jp++){
      int na = n0 + wcol + jp*32 + lr;
      float bva = bias[(size_t)b * bbstride + na];
      float bvg = bias[(size_t)b * bbstride + na + 16];
      int chan = ((n0 + wcol) >> 1) + jp*16 + lr;
      #pragma unroll
      for (int i = 0; i < 4; i++){
        int sr = s0 + wrow + i*16 + lg*4;
        #pragma unroll
        for (int r = 0; r < 4; r++){
          float av = acc[i][jp*2][r]   + bva;
          float gv = acc[i][jp*2+1][r] + bvg;
          size_t oidx = ((size_t)b * S + sr + r) * 128 + chan;
          OUTf[oidx] += leak * av * (1.f / (1.f + expf(-gv)));
        }
      }
    }
  } else {
    #pragma unroll
    for (int j = 0; j < 4; j++){
      int n = n0 + wcol + j*16 + lr;
      if (n >= Mout) continue;
      float bv = bias[(size_t)b * bbstride + n];
      #pragma unroll
      for (int i = 0; i < 4; i++){
        int sr = s0 + wrow + i*16 + lg*4;
        size_t base = ((size_t)b * S + sr) * ldc + n;
        #pragma unroll
        for (int r = 0; r < 4; r++){
          float v = acc[i][j][r] + bv;
          if (RELU) v = fmaxf(v, 0.f);
          stf(OUTp, base + (size_t)r * ldc, v);
        }
      }
    }
  }
}

// ---------------- gaussian blur channel-last ----------------
__global__ __launch_bounds__(256) void k_blur(const float* __restrict__ src,
    float* __restrict__ dst, int H, int S){
  const float G0 = 0.27406862f, G1 = 0.45186276f;
  int idx = blockIdx.x*256 + threadIdx.x;
  int c = idx & 127;
  int s = (idx >> 7) % S;
  int b = idx / (S*128);
  int y = s / H, x = s - y*H;
  const float* sb = src + (size_t)b*S*128 + c;
  float g[3] = {G0, G1, G0};
  float acc = 0.f;
  #pragma unroll
  for (int dy = 0; dy < 3; dy++)
    #pragma unroll
    for (int dx = 0; dx < 3; dx++){
      int yy = y + dy - 1, xx = x + dx - 1;
      float v = (yy>=0 && yy<H && xx>=0 && xx<H) ? sb[(size_t)(yy*H+xx)*128] : 0.f;
      acc += v * g[dy] * g[dx];
    }
  dst[idx] = acc;
}

// ---------------- 2x2 mean pool channel-last ----------------
__global__ __launch_bounds__(256) void k_pool(const float* __restrict__ src,
    float* __restrict__ dst, int H2, int S2){
  int idx = blockIdx.x*256 + threadIdx.x;   // 16*S2*128
  int c = idx & 127;
  int s2 = (idx >> 7) % S2;
  int b = idx / (S2*128);
  int y = s2 / H2, x = s2 - y*H2;
  int W = H2*2;
  const float* sb = src + (size_t)b*(4*S2)*128 + c;
  dst[idx] = 0.25f*( sb[(size_t)((2*y)*W + 2*x)*128]   + sb[(size_t)((2*y)*W + 2*x+1)*128]
                   + sb[(size_t)((2*y+1)*W + 2*x)*128] + sb[(size_t)((2*y+1)*W + 2*x+1)*128]);
}

// ---------------- add seed (seed is channel-first [128][256]) ----------------
__global__ __launch_bounds__(256) void k_seed(float* __restrict__ out,
    const float* __restrict__ seed){
  int idx = blockIdx.x*256 + threadIdx.x;   // 16*256*128
  int c = idx & 127;
  int s = (idx >> 7) & 255;
  out[idx] += seed[c*256 + s];
}

// ---------------- build cs (16,4480) from Ohead [16][256][385] ----------------
__global__ __launch_bounds__(256) void k_build_cs(const float* __restrict__ O,
    float* __restrict__ cs){
  int b = blockIdx.x;
  const float* Ob = O + (size_t)b*256*385;
  for (int id = threadIdx.x; id < 4480; id += 256){
    float v;
    if (id < 128){
      float s = 0; for (int t = 0; t < 256; t++) s += Ob[(size_t)t*385 + id];
      v = s * (1.f/256.f);
    } else if (id < 2176){
      int r = id - 128; int c = r >> 4, h = r & 15;
      float s = 0; for (int w = 0; w < 16; w++) s += Ob[(size_t)(h*16+w)*385 + 128 + c];
      v = s * (1.f/16.f);
    } else if (id < 4224){
      int r = id - 2176; int c = r >> 4, w = r & 15;
      float s = 0; for (int h = 0; h < 16; h++) s += Ob[(size_t)(h*16+w)*385 + 256 + c];
      v = s * (1.f/16.f);
    } else {
      v = Ob[(size_t)(id - 4224)*385 + 384];
    }
    cs[b*4480 + id] = v;
  }
}

// ---------------- small 16-row GEMM: one wave per output row of W ----------------
template<int RELU, int ACCUM, class TOUT>
__global__ __launch_bounds__(256) void k_rowgemm(const float* __restrict__ IN, // [16][K]
    const float* __restrict__ W,    // [M][K]
    const float* __restrict__ bias, // [M]
    TOUT* __restrict__ OUT, int M, int K){
  int wave = (int)((blockIdx.x*256 + threadIdx.x) >> 6);
  int lane = threadIdx.x & 63;
  if (wave >= M) return;
  const float* wr = W + (size_t)wave*K;
  float acc[16] = {};
  for (int k = lane; k < K; k += 64){
    float wv = wr[k];
    #pragma unroll
    for (int b = 0; b < 16; b++) acc[b] += wv * IN[b*K + k];
  }
  #pragma unroll
  for (int b = 0; b < 16; b++)
    for (int off = 32; off > 0; off >>= 1) acc[b] += __shfl_down(acc[b], off);
  if (lane == 0){
    float bv = bias[wave];
    #pragma unroll
    for (int b = 0; b < 16; b++){
      float v = acc[b] + bv;
      if (RELU) v = fmaxf(v, 0.f);
      size_t oi = (size_t)b*M + wave;
      if (ACCUM) v += ldf(OUT, oi);
      stf(OUT, oi, v);
    }
  }
}

extern "C" void kernel_launch(void* const* d_in, const int* in_sizes, int n_in,
                              void* d_out, int out_size, void* d_ws, size_t ws_size,
                              hipStream_t stream){
  (void)in_sizes; (void)n_in; (void)out_size; (void)ws_size;
  const float* x      = (const float*)d_in[0];
  const float* inj    = (const float*)d_in[1];
  const float* leakp  = (const float*)d_in[2];
  const float* in_w   = (const float*)d_in[3];
  const float* in_b   = (const float*)d_in[4];
  const float* fc_w1  = (const float*)d_in[5];
  const float* fc_b1  = (const float*)d_in[6];
  const float* fc_w2  = (const float*)d_in[7];
  const float* fc_b2  = (const float*)d_in[8];
  const float* fc_wsc = (const float*)d_in[9];
  const float* fc_bsc = (const float*)d_in[10];
  const float* hyp_w  = (const float*)d_in[11];
  const float* hyp_b  = (const float*)d_in[12];
  const float* lat_w  = (const float*)d_in[13];
  const float* lat_b  = (const float*)d_in[14];
  const float* seed   = (const float*)d_in[15];
  const float* out_w  = (const float*)d_in[16];
  const float* out_b  = (const float*)d_in[17];
  const float* l1_w1  = (const float*)d_in[18];
  const float* l1_b1  = (const float*)d_in[19];
  const float* l1_w2  = (const float*)d_in[20];
  const float* l1_b2  = (const float*)d_in[21];
  const float* l1_wsc = (const float*)d_in[22];
  const float* l1_bsc = (const float*)d_in[23];
  const float* l2_w1  = (const float*)d_in[24];
  const float* l2_b1  = (const float*)d_in[25];
  const float* l2_w2  = (const float*)d_in[26];
  const float* l2_b2  = (const float*)d_in[27];
  const float* l2_wsc = (const float*)d_in[28];
  const float* l2_bsc = (const float*)d_in[29];
  const float* fin_w  = (const float*)d_in[30];
  const float* fin_b  = (const float*)d_in[31];

  char* ws = (char*)d_ws;
  float* OUT    = (float*)(ws);                      // 32MB  [16][4096][128] fp32
  bf16*  P      = (bf16*)(ws + 33554432UL);          // 48MB  [16][4096][384] (+blur tmp)
  bf16*  HG     = (bf16*)(ws + 83886080UL);          // 32MB  [16][4096][256]
  bf16*  G2     = (bf16*)(ws + 117440512UL);         // 16MB  [16][4096][128]
  float* HKALL  = (float*)(ws + 134217728UL);        // 151.6MB [12][16][197376]
  bf16*  WSTK   = (bf16*)(ws + 285802496UL);         // 3.1MB [16][256][384]
  bf16*  WBIG   = (bf16*)(ws + 288948224UL);         // 5.2MB [16][256][640]
  bf16*  WMD    = (bf16*)(ws + 294191104UL);         // 512KB [16][128][128]
  float* BSTK   = (float*)(ws + 294715392UL);        // [16][256]
  float* BBIG   = (float*)(ws + 294731776UL);        // [16][256]
  float* BMD    = (float*)(ws + 294748160UL);        // [16][128]
  float* SUMS   = (float*)(ws + 294756352UL);        // [16][384][2]
  bf16*  LATB   = (bf16*)(ws + 294805504UL);         // [12][16][512]
  bf16*  OUTB   = (bf16*)(ws + 295002112UL);         // [16][256][128]
  float* OHEAD  = (float*)(ws + 296050688UL);        // [16][256][385]
  bf16*  OWB    = (bf16*)(ws + 302358528UL);         // [385][128]
  float* CS     = (float*)(ws + 302457088UL);        // [16][4480]
  float* T1     = (float*)(ws + 302743808UL);        // [16][1024]
  float* HCS    = (float*)(ws + 302809344UL);        // [16][512]
  float* HCS2   = (float*)(ws + 302842112UL);        // [16][512]

  k_cvt_bf16<<<32, 256, 0, stream>>>(out_w, OWB, 49280ULL);
  k_in_conv<<<32768, 256, 0, stream>>>(x, in_w, in_b, OUT);

  // all 12 latc projections in one launch
  k_latall<<<1536, 256, 0, stream>>>(inj, lat_w, lat_b, LATB);
  // one pass over hyp_w (fp32, coalesced + LDS-staged) computes hk for all 12 cells
  k_hyper_all<<<1542, 256, 0, stream>>>(hyp_w, hyp_b, LATB, HKALL);

  int H = 64;
  for (int c = 0; c < 12; c++){
    int S = H*H;
    int nEl = 16*S*128;
    k_sobel<<<nEl/256, 256, 0, stream>>>(OUT, P, H, S);
    hipMemsetAsync(SUMS, 0, 16*384*2*sizeof(float), stream);
    k_stats<<<dim3(16,16), 256, 0, stream>>>(P, SUMS, S);
    k_xform<<<2560, 256, 0, stream>>>(fc_w1, fc_b1, fc_w2, fc_b2, fc_wsc, fc_bsc,
                                      HKALL + (size_t)c*16*KHK, SUMS, (float)S,
                                      WSTK, BSTK, WBIG, BBIG, WMD, BMD);
    Seg segP  = {P, 384, 384};
    Seg segH1 = {HG, 128, 256};
    Seg segHm = {HG + 128, 128, 256};
    Seg segG2 = {G2, 128, 128};
    k_mfgemm<1,1,0,bf16><<<dim3(S/128, 2, 16), 256, 0, stream>>>(
        segP, segP, segP, WSTK, 98304LL, 384, BSTK, 256, HG, 256, 256, S, nullptr);
    k_mfgemm<1,1,0,bf16><<<dim3(S/128, 1, 16), 256, 0, stream>>>(
        segHm, segHm, segHm, WMD, 16384LL, 128, BMD, 128, G2, 128, 128, S, nullptr);
    // fused: computes d+f (a/g interleaved cols) and applies OUT += leak*a*sigmoid(g)
    k_mfgemm<0,3,1,float><<<dim3(S/128, 2, 16), 256, 0, stream>>>(
        segP, segH1, segG2, WBIG, 163840LL, 640, BBIG, 256, OUT, 128, 256, S, leakp);
    if (c == 3 || c == 7){
      k_blur<<<nEl/256, 256, 0, stream>>>(OUT, (float*)P, H, S);
      int H2 = H/2, S2 = S/4;
      k_pool<<<(16*S2*128)/256, 256, 0, stream>>>((float*)P, OUT, H2, S2);
      H = H2;
    }
  }

  k_seed<<<2048, 256, 0, stream>>>(OUT, seed);
  k_cvt_bf16<<<256, 256, 0, stream>>>(OUT, OUTB, 524288ULL);
  Seg segO = {OUTB, 128, 128};
  k_mfgemm<0,1,0,float><<<dim3(2, 4, 16), 256, 0, stream>>>(
      segO, segO, segO, OWB, 0LL, 128, out_b, 0, OHEAD, 385, 385, 256, nullptr);
  k_build_cs<<<16, 256, 0, stream>>>(OHEAD, CS);

  k_rowgemm<1,0,float><<<256, 256, 0, stream>>>(CS,  l1_w1,  l1_b1,  T1,   1024, 4480);
  k_rowgemm<0,0,float><<<128, 256, 0, stream>>>(CS,  l1_wsc, l1_bsc, HCS,  512, 4480);
  k_rowgemm<0,1,float><<<128, 256, 0, stream>>>(T1,  l1_w2,  l1_b2,  HCS,  512, 1024);
  k_rowgemm<1,0,float><<<128, 256, 0, stream>>>(HCS, l2_w1,  l2_b1,  T1,   512, 512);
  k_rowgemm<0,0,float><<<128, 256, 0, stream>>>(HCS, l2_wsc, l2_bsc, HCS2, 512, 512);
  k_rowgemm<0,1,float><<<128, 256, 0, stream>>>(T1,  l2_w2,  l2_b2,  HCS2, 512, 512);
  k_rowgemm<0,0,float><<<128, 256, 0, stream>>>(HCS2, fin_w, fin_b, (float*)d_out, 512, 512);
}